// Round 1
// 526.520 us; speedup vs baseline: 1.1923x; 1.1923x over previous
//
#include <hip/hip_runtime.h>
#include <math.h>

// Problem constants
#define Kn    30
#define Hn    128
#define NB    2048          // nodes per batch
#define YS    136           // row stride (128 + 8 pad): 17 16B-groups (odd) -> conflict-free b128

// ws layout: bf16 weights, then fp32 scratch
#define OFF_W1    0
#define OFF_W2    49152
#define OFF_W3    65536
#define OFF_W11   81920
#define OFF_W12   131072
#define OFF_W13   147456
#define OFF_WIN   163840
#define OFF_WOUT  229376
#define W_TOTAL   294912
// fp32 scratch offsets (in floats, relative to end of weight region)
#define WS_HMID   0
#define WS_SS     1048576   // self-term: s1self, then (aliased) s11self
#define WS_SN     2097152   // nbr-term:  s1nbr,  then (aliased) s11nbr

typedef __attribute__((ext_vector_type(8)))  short bh8;
typedef __attribute__((ext_vector_type(4)))  short bh4;
typedef __attribute__((ext_vector_type(16))) float fx16;

__device__ __forceinline__ unsigned short f2bf(float f) {
    unsigned int u = __float_as_uint(f);
    u += 0x7fffu + ((u >> 16) & 1u);        // RNE
    return (unsigned short)(u >> 16);
}
__device__ __forceinline__ float bf2f(unsigned short h) {
    return __uint_as_float(((unsigned int)h) << 16);
}
// tanh-form GELU via v_exp_f32 (|err vs erf-GELU| <~1e-3, cheap: ~8 VALU ops)
__device__ __forceinline__ float gelu_f(float x) {
    float u = 0.7978845608028654f * x * (1.0f + 0.044715f * x * x);
    return x / (1.0f + __expf(-2.0f * u));
}
__device__ __forceinline__ fx16 mfma_bf16(bh8 a, bh8 b, fx16 c) {
    return __builtin_amdgcn_mfma_f32_32x32x16_bf16(a, b, c, 0, 0, 0);
}
__device__ __forceinline__ void st_bf4(unsigned short* dst, float4 v) {
    bh4 t;
    t.x = (short)f2bf(v.x); t.y = (short)f2bf(v.y);
    t.z = (short)f2bf(v.z); t.w = (short)f2bf(v.w);
    *(bh4*)dst = t;                          // ds_write_b64
}

// Fully-unrolled K-loop: one A row-tile (32 rows) x two B n-tiles.
template<int KS>
__device__ __forceinline__ void gemm_pair(const unsigned short* __restrict__ aBase,
                                          const unsigned short* __restrict__ b0,
                                          const unsigned short* __restrict__ b1,
                                          fx16& acc0, fx16& acc1) {
    #pragma unroll
    for (int ks = 0; ks < KS; ks++) {
        bh8 a = *(const bh8*)(aBase + ks * 16);
        acc0 = mfma_bf16(a, *(const bh8*)(b0 + ks * 16), acc0);
        acc1 = mfma_bf16(a, *(const bh8*)(b1 + ks * 16), acc1);
    }
}

// C-layout (verified m74/m101): col = lane&31, row = (reg&3)+8*(reg>>2)+4*(lane>>5)
// epilogue with self-term (LDS) + prefetched nbr-term (regs) + bias + gelu
__device__ __forceinline__ void epi_gelu_sp(const fx16& ac, int col, int rowBase,
                                            float bias, const float* __restrict__ sSelf,
                                            const float* pre,
                                            unsigned short* __restrict__ dst, int lane) {
    int ro = rowBase + 4 * (lane >> 5);
    #pragma unroll
    for (int r = 0; r < 16; r++) {
        int row = ro + (r & 3) + 8 * (r >> 2);
        float st = sSelf[((row >= Kn) ? 128 : 0) + col];
        dst[row * YS + col] = f2bf(gelu_f(ac[r] + bias + st + pre[r]));
    }
}
__device__ __forceinline__ void epi_gelu(const fx16& ac, int col, int rowBase,
                                         float bias, unsigned short* __restrict__ dst,
                                         int lane) {
    int ro = rowBase + 4 * (lane >> 5);
    #pragma unroll
    for (int r = 0; r < 16; r++) {
        int row = ro + (r & 3) + 8 * (r >> 2);
        dst[row * YS + col] = f2bf(gelu_f(ac[r] + bias));
    }
}
__device__ __forceinline__ void epi_plain(const fx16& ac, int col, int rowBase,
                                          float bias, unsigned short* __restrict__ dst,
                                          int lane) {
    int ro = rowBase + 4 * (lane >> 5);
    #pragma unroll
    for (int r = 0; r < 16; r++) {
        int row = ro + (r & 3) + 8 * (r >> 2);
        dst[row * YS + col] = f2bf(ac[r] + bias);
    }
}

// ---------------------------------------------------------------------------
// prep: fp32 -> bf16 weights into workspace
// ---------------------------------------------------------------------------
__global__ __launch_bounds__(256) void prep_weights(
    const float* __restrict__ W1, const float* __restrict__ W2,
    const float* __restrict__ W3, const float* __restrict__ W11,
    const float* __restrict__ W12, const float* __restrict__ W13,
    const float* __restrict__ Win, const float* __restrict__ Wout,
    unsigned short* __restrict__ wsbf) {
    int i = blockIdx.x * 256 + threadIdx.x;
    if (i >= W_TOTAL) return;
    float v;
    if      (i < OFF_W2)   v = W1[i - OFF_W1];
    else if (i < OFF_W3)   v = W2[i - OFF_W2];
    else if (i < OFF_W11)  v = W3[i - OFF_W3];
    else if (i < OFF_W12)  v = W11[i - OFF_W11];
    else if (i < OFF_W13)  v = W12[i - OFF_W12];
    else if (i < OFF_WIN)  v = W13[i - OFF_W13];
    else if (i < OFF_WOUT) v = Win[i - OFF_WIN];
    else                   v = Wout[i - OFF_WOUT];
    wsbf[i] = f2bf(v);
}

// ---------------------------------------------------------------------------
// self+nbr terms for node GEMM1:
//   s1s[p] = h_V[p] @ W1[:,0:128]^T      (self columns)
//   s1n[p] = h_V[p] @ W1[:,256:384]^T    (neighbor columns; gathered later)
// 256 blocks x 32 rows, 4 waves, each wave one 32-col n-tile.
// ---------------------------------------------------------------------------
__global__ __launch_bounds__(256) void self_gemm(
    const float* __restrict__ hv, const unsigned short* __restrict__ wsbf,
    float* __restrict__ s1s, float* __restrict__ s1n) {
    __shared__ __align__(16) unsigned short sA[32 * YS];
    const int tid = threadIdx.x;
    const int p0 = blockIdx.x * 32;
    const unsigned short* W1bf = wsbf + OFF_W1;
    for (int i = tid; i < 1024; i += 256) {
        int r = i >> 5, c4 = (i & 31) << 2;
        float4 v = *(const float4*)(hv + (size_t)(p0 + r) * Hn + c4);
        st_bf4(sA + r * YS + c4, v);
    }
    __syncthreads();
    const int wid = tid >> 6, lane = tid & 63;
    const int lane31 = lane & 31, lk = (lane >> 5) << 3;
    fx16 accS = {}, accN = {};
    const unsigned short* a   = sA + lane31 * YS + lk;
    const unsigned short* bwS = W1bf + (size_t)(32 * wid + lane31) * 384 + lk;        // cols 0..127
    const unsigned short* bwN = bwS + 256;                                            // cols 256..383
    #pragma unroll
    for (int ks = 0; ks < 8; ks++) {
        bh8 av = *(const bh8*)(a + ks * 16);
        accS = mfma_bf16(av, *(const bh8*)(bwS + ks * 16), accS);
        accN = mfma_bf16(av, *(const bh8*)(bwN + ks * 16), accN);
    }
    int col = 32 * wid + lane31;
    #pragma unroll
    for (int r = 0; r < 16; r++) {
        int row = (r & 3) + 8 * (r >> 2) + 4 * (lane >> 5);
        s1s[(size_t)(p0 + row) * Hn + col] = accS[r];
        s1n[(size_t)(p0 + row) * Hn + col] = accN[r];
    }
}

// ---------------------------------------------------------------------------
// Kernel A: node message MLP + masked mean + residual + LN1 -> hmid (fp32)
// G=2 nodes/block, M=60(pad 64). GEMM1 K reduced to 128 (h_E only): the
// neighbor term is precomputed per node (s1n) and gathered in the epilogue.
// LDS ~36.5 KB -> 4 blocks/CU.
// ---------------------------------------------------------------------------
__global__ __launch_bounds__(256, 4) void node_update_mfma(
    const float* __restrict__ h_V, const float* __restrict__ h_E,
    const int* __restrict__ E_idx, const float* __restrict__ mask_attend,
    const unsigned short* __restrict__ wsbf,
    const float* __restrict__ s1s, const float* __restrict__ s1n,
    const float* __restrict__ W1_b, const float* __restrict__ W2_b,
    const float* __restrict__ W3_b,
    const float* __restrict__ g1v, const float* __restrict__ b1v,
    float* __restrict__ hmid) {
    __shared__ __align__(16) unsigned short sX[64 * YS]; // h_E; fp32 scratch after GEMM1
    __shared__ __align__(16) unsigned short sY[64 * YS];
    __shared__ float sS1[256];
    __shared__ float sMask[64];
    __shared__ int   sIdx[64];
    __shared__ float sStats[4];

    const int tid = threadIdx.x;
    const int p0 = blockIdx.x * 2;
    const int bB = p0 >> 11;
    const unsigned short* W1bf = wsbf + OFF_W1;
    const unsigned short* W2bf = wsbf + OFF_W2;
    const unsigned short* W3bf = wsbf + OFF_W3;

    // ---- staging: h_E only ----
    for (int i = tid; i < 1920; i += 256) {
        int r = i >> 5, c4 = (i & 31) << 2;
        float4 v = *(const float4*)(h_E + ((size_t)(p0 * Kn + r)) * Hn + c4);
        st_bf4(sX + r * YS + c4, v);
    }
    for (int i = tid; i < 272; i += 256)             // zero pad rows 60..63
        ((unsigned int*)(sX + 60 * YS))[i] = 0;
    if (tid < 64) {
        int g = tid >> 5, c4 = (tid & 31) << 2;
        *(float4*)(sS1 + g * 128 + c4) = *(const float4*)(s1s + (size_t)(p0 + g) * Hn + c4);
    }
    if (tid < 60) sMask[tid] = mask_attend[p0 * Kn + tid];
    if (tid < 64) sIdx[tid] = (tid < 60) ? E_idx[p0 * Kn + tid] : 0;
    __syncthreads();

    const int wid = tid >> 6, lane = tid & 63;
    const int mt = wid & 1, np = wid >> 1;
    const int lane31 = lane & 31, lk = (lane >> 5) << 3;
    const int rowBase = 32 * mt;
    const fx16 zv = {};
    const int c0 = 64 * np + lane31, c1 = c0 + 32;

    // ---- prefetch gathered neighbor term (s1n, L2-resident) into regs;
    //      latency hides under GEMM1's MFMAs ----
    float pre0[16], pre1[16];
    #pragma unroll
    for (int r = 0; r < 16; r++) {
        int row = rowBase + 4 * (lane >> 5) + (r & 3) + 8 * (r >> 2);
        const float* sp = s1n + (size_t)(bB * NB + sIdx[row]) * Hn;
        pre0[r] = sp[c0];
        pre1[r] = sp[c1];
    }

    // ---- GEMM1: X[64,128] @ W1[:,128:256]^T + s1s + s1n + b -> GELU -> Y ----
    fx16 acc0 = zv, acc1 = zv;
    gemm_pair<8>(sX + (rowBase + lane31) * YS + lk,
                 W1bf + (64 * np + lane31) * 384 + 128 + lk,
                 W1bf + (64 * np + 32 + lane31) * 384 + 128 + lk, acc0, acc1);
    epi_gelu_sp(acc0, c0, rowBase, W1_b[c0], sS1, pre0, sY, lane);
    epi_gelu_sp(acc1, c1, rowBase, W1_b[c1], sS1, pre1, sY, lane);
    __syncthreads();

    // ---- GEMM2 (in place, sync-guarded) ----
    acc0 = zv; acc1 = zv;
    gemm_pair<8>(sY + (rowBase + lane31) * YS + lk,
                 W2bf + (64 * np + lane31) * 128 + lk,
                 W2bf + (64 * np + 32 + lane31) * 128 + lk, acc0, acc1);
    __syncthreads();
    epi_gelu(acc0, c0, rowBase, W2_b[c0], sY, lane);
    epi_gelu(acc1, c1, rowBase, W2_b[c1], sY, lane);
    __syncthreads();

    // ---- GEMM3 + masked k-reduction (partials into fp32 scratch over sX) ----
    acc0 = zv; acc1 = zv;
    gemm_pair<8>(sY + (rowBase + lane31) * YS + lk,
                 W3bf + (64 * np + lane31) * 128 + lk,
                 W3bf + (64 * np + 32 + lane31) * 128 + lk, acc0, acc1);
    float* fbuf = (float*)sX;                        // sX dead after GEMM1
    #pragma unroll
    for (int t = 0; t < 2; t++) {
        const fx16& ac = t ? acc1 : acc0;
        int col = t ? c1 : c0;
        float bias = W3_b[col];
        float sA0 = 0.f, sA1 = 0.f;
        #pragma unroll
        for (int r = 0; r < 16; r++) {
            int row = rowBase + (r & 3) + 8 * (r >> 2) + 4 * (lane >> 5);
            if (row < 60) {
                float v = (ac[r] + bias) * sMask[row];
                if (row < Kn) sA0 += v; else sA1 += v;
            }
        }
        sA0 += __shfl_down(sA0, 32);
        sA1 += __shfl_down(sA1, 32);
        if (lane < 32) { fbuf[mt * 256 + col] = sA0; fbuf[mt * 256 + 128 + col] = sA1; }
    }
    __syncthreads();

    // ---- residual + LN1 -> hmid ----
    float* xbuf = fbuf + 512;
    {
        int g = tid >> 7, c = tid & 127;
        float x = h_V[(size_t)(p0 + g) * Hn + c] +
                  (fbuf[g * 128 + c] + fbuf[256 + g * 128 + c]) * (1.0f / 30.0f);
        xbuf[g * 128 + c] = x;
    }
    __syncthreads();
    if (wid < 2) {
        float x0 = xbuf[wid * 128 + lane], x1 = xbuf[wid * 128 + 64 + lane];
        float s = x0 + x1, q = x0 * x0 + x1 * x1;
        #pragma unroll
        for (int off = 32; off; off >>= 1) { s += __shfl_down(s, off); q += __shfl_down(q, off); }
        if (lane == 0) {
            float mean = s * 0.0078125f;
            sStats[wid * 2] = mean;
            sStats[wid * 2 + 1] = rsqrtf(q * 0.0078125f - mean * mean + 1e-5f);
        }
    }
    __syncthreads();
    {
        int g = tid >> 7, c = tid & 127;
        float hv = (xbuf[g * 128 + c] - sStats[g * 2]) * sStats[g * 2 + 1] * g1v[c] + b1v[c];
        hmid[(size_t)(p0 + g) * Hn + c] = hv;
    }
}

// ---------------------------------------------------------------------------
// Kernel B: FFN + LN2 + mask_V -> hV_out, then s11s/s11n = hV_out @ W11{self,nbr}^T.
// 256 blocks x 32 rows, full MFMA row utilization, chunked K over hidden=512.
// ---------------------------------------------------------------------------
__global__ __launch_bounds__(256) void ffn_fused(
    const float* __restrict__ hmid, const float* __restrict__ mask_V,
    const unsigned short* __restrict__ wsbf,
    const float* __restrict__ Win_b, const float* __restrict__ Wout_b,
    const float* __restrict__ g2v, const float* __restrict__ b2v,
    float* __restrict__ hV_out, float* __restrict__ s11s, float* __restrict__ s11n) {
    __shared__ __align__(16) unsigned short sA[32 * YS];  // hmid bf16
    __shared__ __align__(16) unsigned short sH[32 * YS];  // hidden chunk bf16
    __shared__ __align__(16) float sO[32 * 132];          // FFN-out fp32
    __shared__ __align__(16) unsigned short sV[32 * YS];  // hV_out bf16 for s11

    const int tid = threadIdx.x;
    const int p0 = blockIdx.x * 32;
    const unsigned short* Winbf  = wsbf + OFF_WIN;
    const unsigned short* Woutbf = wsbf + OFF_WOUT;
    const unsigned short* W11bf  = wsbf + OFF_W11;

    for (int i = tid; i < 1024; i += 256) {
        int r = i >> 5, c4 = (i & 31) << 2;
        float4 v = *(const float4*)(hmid + (size_t)(p0 + r) * Hn + c4);
        st_bf4(sA + r * YS + c4, v);
    }
    __syncthreads();

    const int wid = tid >> 6, lane = tid & 63;
    const int lane31 = lane & 31, lk = (lane >> 5) << 3;
    const fx16 zv = {};
    fx16 accO = zv;

    for (int c = 0; c < 4; c++) {
        int hcol = 128 * c + 32 * wid + lane31;
        fx16 t = zv;
        {
            const unsigned short* a  = sA + lane31 * YS + lk;
            const unsigned short* bw = Winbf + (size_t)hcol * 128 + lk;
            #pragma unroll
            for (int ks = 0; ks < 8; ks++)
                t = mfma_bf16(*(const bh8*)(a + ks * 16), *(const bh8*)(bw + ks * 16), t);
        }
        float bias = Win_b[hcol];
        int colL = 32 * wid + lane31;
        #pragma unroll
        for (int r = 0; r < 16; r++) {
            int row = (r & 3) + 8 * (r >> 2) + 4 * (lane >> 5);
            sH[row * YS + colL] = f2bf(gelu_f(t[r] + bias));
        }
        __syncthreads();
        {
            const unsigned short* a  = sH + lane31 * YS + lk;
            const unsigned short* bw = Woutbf + (size_t)(32 * wid + lane31) * 512 + 128 * c + lk;
            #pragma unroll
            for (int ks = 0; ks < 8; ks++)
                accO = mfma_bf16(*(const bh8*)(a + ks * 16), *(const bh8*)(bw + ks * 16), accO);
        }
        __syncthreads();
    }
    {
        int col = 32 * wid + lane31;
        float bias = Wout_b[col];
        #pragma unroll
        for (int r = 0; r < 16; r++) {
            int row = (r & 3) + 8 * (r >> 2) + 4 * (lane >> 5);
            sO[row * 132 + col] = accO[r] + bias;
        }
    }
    __syncthreads();
    for (int r = wid; r < 32; r += 4) {
        float x0 = sO[r * 132 + lane]      + hmid[(size_t)(p0 + r) * Hn + lane];
        float x1 = sO[r * 132 + 64 + lane] + hmid[(size_t)(p0 + r) * Hn + 64 + lane];
        float s = x0 + x1, q = x0 * x0 + x1 * x1;
        #pragma unroll
        for (int off = 32; off; off >>= 1) { s += __shfl_down(s, off); q += __shfl_down(q, off); }
        s = __shfl(s, 0); q = __shfl(q, 0);
        float mean = s * 0.0078125f;
        float rstd = rsqrtf(q * 0.0078125f - mean * mean + 1e-5f);
        float mv = mask_V[p0 + r];
        float y0 = ((x0 - mean) * rstd * g2v[lane]      + b2v[lane])      * mv;
        float y1 = ((x1 - mean) * rstd * g2v[lane + 64] + b2v[lane + 64]) * mv;
        hV_out[(size_t)(p0 + r) * Hn + lane]      = y0;
        hV_out[(size_t)(p0 + r) * Hn + 64 + lane] = y1;
        sV[r * YS + lane]      = f2bf(y0);
        sV[r * YS + 64 + lane] = f2bf(y1);
    }
    __syncthreads();
    {
        int col = 32 * wid + lane31;
        fx16 accS = zv, accN = zv;
        const unsigned short* a   = sV + lane31 * YS + lk;
        const unsigned short* bwS = W11bf + (size_t)col * 384 + lk;        // self cols 0..127
        const unsigned short* bwN = W11bf + (size_t)col * 384 + 256 + lk;  // nbr  cols 256..383
        #pragma unroll
        for (int ks = 0; ks < 8; ks++) {
            bh8 av = *(const bh8*)(a + ks * 16);
            accS = mfma_bf16(av, *(const bh8*)(bwS + ks * 16), accS);
            accN = mfma_bf16(av, *(const bh8*)(bwN + ks * 16), accN);
        }
        #pragma unroll
        for (int r = 0; r < 16; r++) {
            int row = (r & 3) + 8 * (r >> 2) + 4 * (lane >> 5);
            s11s[(size_t)(p0 + row) * Hn + col] = accS[r];
            s11n[(size_t)(p0 + row) * Hn + col] = accN[r];
        }
    }
}

// ---------------------------------------------------------------------------
// Kernel C: edge update (reads updated h_V via precomputed s11s/s11n), per-row LN.
// GEMM1 K reduced to 128 (h_E only); neighbor term gathered from s11n.
// ---------------------------------------------------------------------------
__global__ __launch_bounds__(256, 4) void edge_update_mfma(
    const float* __restrict__ h_E, const int* __restrict__ E_idx,
    const unsigned short* __restrict__ wsbf,
    const float* __restrict__ s11s, const float* __restrict__ s11n,
    const float* __restrict__ W11_b, const float* __restrict__ W12_b,
    const float* __restrict__ W13_b,
    const float* __restrict__ g3v, const float* __restrict__ b3v,
    float* __restrict__ hE_out) {
    __shared__ __align__(16) unsigned short sX[64 * YS]; // h_E, live to end (residual)
    __shared__ __align__(16) unsigned short sY[64 * YS];
    __shared__ float sS11[256];
    __shared__ int   sIdx[64];

    const int tid = threadIdx.x;
    const int p0 = blockIdx.x * 2;
    const int bB = p0 >> 11;
    const unsigned short* W11bf = wsbf + OFF_W11;
    const unsigned short* W12bf = wsbf + OFF_W12;
    const unsigned short* W13bf = wsbf + OFF_W13;

    for (int i = tid; i < 1920; i += 256) {
        int r = i >> 5, c4 = (i & 31) << 2;
        float4 v = *(const float4*)(h_E + ((size_t)(p0 * Kn + r)) * Hn + c4);
        st_bf4(sX + r * YS + c4, v);
    }
    for (int i = tid; i < 272; i += 256)
        ((unsigned int*)(sX + 60 * YS))[i] = 0;
    if (tid < 64) {
        int g = tid >> 5, c4 = (tid & 31) << 2;
        *(float4*)(sS11 + g * 128 + c4) = *(const float4*)(s11s + (size_t)(p0 + g) * Hn + c4);
    }
    if (tid < 64) sIdx[tid] = (tid < 60) ? E_idx[p0 * Kn + tid] : 0;
    __syncthreads();

    const int wid = tid >> 6, lane = tid & 63;
    const int mt = wid & 1, np = wid >> 1;
    const int lane31 = lane & 31, lk = (lane >> 5) << 3;
    const int rowBase = 32 * mt;
    const fx16 zv = {};
    const int c0 = 64 * np + lane31, c1 = c0 + 32;

    // prefetch gathered neighbor term (s11n, L2-resident)
    float pre0[16], pre1[16];
    #pragma unroll
    for (int r = 0; r < 16; r++) {
        int row = rowBase + 4 * (lane >> 5) + (r & 3) + 8 * (r >> 2);
        const float* sp = s11n + (size_t)(bB * NB + sIdx[row]) * Hn;
        pre0[r] = sp[c0];
        pre1[r] = sp[c1];
    }

    fx16 acc0 = zv, acc1 = zv;
    gemm_pair<8>(sX + (rowBase + lane31) * YS + lk,
                 W11bf + (64 * np + lane31) * 384 + 128 + lk,
                 W11bf + (64 * np + 32 + lane31) * 384 + 128 + lk, acc0, acc1);
    epi_gelu_sp(acc0, c0, rowBase, W11_b[c0], sS11, pre0, sY, lane);
    epi_gelu_sp(acc1, c1, rowBase, W11_b[c1], sS11, pre1, sY, lane);
    __syncthreads();

    acc0 = zv; acc1 = zv;
    gemm_pair<8>(sY + (rowBase + lane31) * YS + lk,
                 W12bf + (64 * np + lane31) * 128 + lk,
                 W12bf + (64 * np + 32 + lane31) * 128 + lk, acc0, acc1);
    __syncthreads();
    epi_gelu(acc0, c0, rowBase, W12_b[c0], sY, lane);
    epi_gelu(acc1, c1, rowBase, W12_b[c1], sY, lane);
    __syncthreads();

    acc0 = zv; acc1 = zv;
    gemm_pair<8>(sY + (rowBase + lane31) * YS + lk,
                 W13bf + (64 * np + lane31) * 128 + lk,
                 W13bf + (64 * np + 32 + lane31) * 128 + lk, acc0, acc1);
    __syncthreads();
    epi_plain(acc0, c0, rowBase, W13_b[c0], sY, lane);
    epi_plain(acc1, c1, rowBase, W13_b[c1], sY, lane);
    __syncthreads();

    // per-edge-row LN over E=128 (residual from bf16 h_E in sX)
    for (int r = wid; r < 60; r += 4) {
        float x0 = bf2f(sX[r * YS + lane])      + bf2f(sY[r * YS + lane]);
        float x1 = bf2f(sX[r * YS + 64 + lane]) + bf2f(sY[r * YS + 64 + lane]);
        float s = x0 + x1, q = x0 * x0 + x1 * x1;
        #pragma unroll
        for (int off = 32; off; off >>= 1) { s += __shfl_down(s, off); q += __shfl_down(q, off); }
        s = __shfl(s, 0); q = __shfl(q, 0);
        float mean = s * 0.0078125f;
        float rstd = rsqrtf(q * 0.0078125f - mean * mean + 1e-5f);
        float* op = hE_out + ((size_t)(p0 * Kn + r)) * 128;
        op[lane]      = (x0 - mean) * rstd * g3v[lane]      + b3v[lane];
        op[lane + 64] = (x1 - mean) * rstd * g3v[lane + 64] + b3v[lane + 64];
    }
}

extern "C" void kernel_launch(void* const* d_in, const int* in_sizes, int n_in,
                              void* d_out, int out_size, void* d_ws, size_t ws_size,
                              hipStream_t stream) {
    const float* h_V         = (const float*)d_in[0];
    const float* h_E         = (const float*)d_in[1];
    const int*   E_idx       = (const int*)  d_in[2];
    const float* mask_V      = (const float*)d_in[3];
    const float* mask_attend = (const float*)d_in[4];
    const float* W1_w  = (const float*)d_in[5];
    const float* W1_b  = (const float*)d_in[6];
    const float* W2_w  = (const float*)d_in[7];
    const float* W2_b  = (const float*)d_in[8];
    const float* W3_w  = (const float*)d_in[9];
    const float* W3_b  = (const float*)d_in[10];
    const float* W11_w = (const float*)d_in[11];
    const float* W11_b = (const float*)d_in[12];
    const float* W12_w = (const float*)d_in[13];
    const float* W12_b = (const float*)d_in[14];
    const float* W13_w = (const float*)d_in[15];
    const float* W13_b = (const float*)d_in[16];
    const float* Win_w  = (const float*)d_in[17];
    const float* Win_b  = (const float*)d_in[18];
    const float* Wout_w = (const float*)d_in[19];
    const float* Wout_b = (const float*)d_in[20];
    const float* g1 = (const float*)d_in[21];
    const float* b1 = (const float*)d_in[22];
    const float* g2 = (const float*)d_in[23];
    const float* b2 = (const float*)d_in[24];
    const float* g3 = (const float*)d_in[25];
    const float* b3 = (const float*)d_in[26];

    float* out    = (float*)d_out;
    float* hV_out = out;                          // [B,N,H]
    float* hE_out = out + (size_t)4 * 2048 * 128; // [B,N,K,E]
    unsigned short* wsbf = (unsigned short*)d_ws;
    float* wsf  = (float*)(wsbf + W_TOTAL);
    float* hmid = wsf + WS_HMID;
    float* sS   = wsf + WS_SS;   // s1 self, then (after A) s11 self
    float* sN   = wsf + WS_SN;   // s1 nbr,  then (after A) s11 nbr

    prep_weights<<<(W_TOTAL + 255) / 256, 256, 0, stream>>>(
        W1_w, W2_w, W3_w, W11_w, W12_w, W13_w, Win_w, Wout_w, wsbf);

    self_gemm<<<256, 256, 0, stream>>>(h_V, wsbf, sS, sN);

    node_update_mfma<<<4096, 256, 0, stream>>>(
        h_V, h_E, E_idx, mask_attend, wsbf, sS, sN,
        W1_b, W2_b, W3_b, g1, b1, hmid);

    ffn_fused<<<256, 256, 0, stream>>>(
        hmid, mask_V, wsbf, Win_b, Wout_b, g2, b2, hV_out, sS, sN);

    edge_update_mfma<<<4096, 256, 0, stream>>>(
        h_E, E_idx, wsbf, sS, sN,
        W11_b, W12_b, W13_b, g3, b3, hE_out);
}

// Round 3
// 503.507 us; speedup vs baseline: 1.2468x; 1.0457x over previous
//
#include <hip/hip_runtime.h>
#include <math.h>

// Problem constants
#define Kn    30
#define Hn    128
#define NB    2048          // nodes per batch
#define YS    136           // row stride (128 + 8 pad): 17 16B-groups (odd) -> conflict-free b128

// ws layout: bf16 weights, then fp32 scratch
#define OFF_W1    0
#define OFF_W2    49152
#define OFF_W3    65536
#define OFF_W11   81920
#define OFF_W12   131072
#define OFF_W13   147456
#define OFF_WIN   163840
#define OFF_WOUT  229376
#define W_TOTAL   294912
// fp32 scratch offsets (in floats, relative to end of weight region)
#define WS_ZM     524288    // zm [8192] fp32 (z bf16 occupies [0,524288) floats)
#define WS_SS     1048576   // self-term: s1self, then (aliased) s11self
#define WS_SN     2097152   // nbr-term:  s1nbr,  then (aliased) s11nbr

typedef __attribute__((ext_vector_type(8)))  short bh8;
typedef __attribute__((ext_vector_type(4)))  short bh4;
typedef __attribute__((ext_vector_type(16))) float fx16;

__device__ __forceinline__ unsigned short f2bf(float f) {
    unsigned int u = __float_as_uint(f);
    u += 0x7fffu + ((u >> 16) & 1u);        // RNE
    return (unsigned short)(u >> 16);
}
__device__ __forceinline__ float bf2f(unsigned short h) {
    return __uint_as_float(((unsigned int)h) << 16);
}
// tanh-form GELU via v_exp_f32 (|err vs erf-GELU| <~1e-3) — R1-exact form
__device__ __forceinline__ float gelu_f(float x) {
    float u = 0.7978845608028654f * x * (1.0f + 0.044715f * x * x);
    return x / (1.0f + __expf(-2.0f * u));
}
__device__ __forceinline__ fx16 mfma_bf16(bh8 a, bh8 b, fx16 c) {
    return __builtin_amdgcn_mfma_f32_32x32x16_bf16(a, b, c, 0, 0, 0);
}
__device__ __forceinline__ void st_bf4(unsigned short* dst, float4 v) {
    bh4 t;
    t.x = (short)f2bf(v.x); t.y = (short)f2bf(v.y);
    t.z = (short)f2bf(v.z); t.w = (short)f2bf(v.w);
    *(bh4*)dst = t;                          // ds_write_b64
}

// Fully-unrolled K-loop: one A row-tile (32 rows) x two B n-tiles.
template<int KS>
__device__ __forceinline__ void gemm_pair(const unsigned short* __restrict__ aBase,
                                          const unsigned short* __restrict__ b0,
                                          const unsigned short* __restrict__ b1,
                                          fx16& acc0, fx16& acc1) {
    #pragma unroll
    for (int ks = 0; ks < KS; ks++) {
        bh8 a = *(const bh8*)(aBase + ks * 16);
        acc0 = mfma_bf16(a, *(const bh8*)(b0 + ks * 16), acc0);
        acc1 = mfma_bf16(a, *(const bh8*)(b1 + ks * 16), acc1);
    }
}

// C-layout (verified m74/m101): col = lane&31, row = (reg&3)+8*(reg>>2)+4*(lane>>5)
// epilogue with self-term (LDS) + prefetched nbr-term (regs) + bias + gelu
__device__ __forceinline__ void epi_gelu_sp(const fx16& ac, int col, int rowBase,
                                            float bias, const float* __restrict__ sSelf,
                                            const float* pre,
                                            unsigned short* __restrict__ dst, int lane) {
    int ro = rowBase + 4 * (lane >> 5);
    #pragma unroll
    for (int r = 0; r < 16; r++) {
        int row = ro + (r & 3) + 8 * (r >> 2);
        float st = sSelf[((row >= Kn) ? 128 : 0) + col];
        dst[row * YS + col] = f2bf(gelu_f(ac[r] + bias + st + pre[r]));
    }
}
__device__ __forceinline__ void epi_gelu(const fx16& ac, int col, int rowBase,
                                         float bias, unsigned short* __restrict__ dst,
                                         int lane) {
    int ro = rowBase + 4 * (lane >> 5);
    #pragma unroll
    for (int r = 0; r < 16; r++) {
        int row = ro + (r & 3) + 8 * (r >> 2);
        dst[row * YS + col] = f2bf(gelu_f(ac[r] + bias));
    }
}
__device__ __forceinline__ void epi_plain(const fx16& ac, int col, int rowBase,
                                          float bias, unsigned short* __restrict__ dst,
                                          int lane) {
    int ro = rowBase + 4 * (lane >> 5);
    #pragma unroll
    for (int r = 0; r < 16; r++) {
        int row = ro + (r & 3) + 8 * (r >> 2);
        dst[row * YS + col] = f2bf(ac[r] + bias);
    }
}

// ---------------------------------------------------------------------------
// prep: fp32 -> bf16 weights into workspace
// ---------------------------------------------------------------------------
__global__ __launch_bounds__(256) void prep_weights(
    const float* __restrict__ W1, const float* __restrict__ W2,
    const float* __restrict__ W3, const float* __restrict__ W11,
    const float* __restrict__ W12, const float* __restrict__ W13,
    const float* __restrict__ Win, const float* __restrict__ Wout,
    unsigned short* __restrict__ wsbf) {
    int i = blockIdx.x * 256 + threadIdx.x;
    if (i >= W_TOTAL) return;
    float v;
    if      (i < OFF_W2)   v = W1[i - OFF_W1];
    else if (i < OFF_W3)   v = W2[i - OFF_W2];
    else if (i < OFF_W11)  v = W3[i - OFF_W3];
    else if (i < OFF_W12)  v = W11[i - OFF_W11];
    else if (i < OFF_W13)  v = W12[i - OFF_W12];
    else if (i < OFF_WIN)  v = W13[i - OFF_W13];
    else if (i < OFF_WOUT) v = Win[i - OFF_WIN];
    else                   v = Wout[i - OFF_WOUT];
    wsbf[i] = f2bf(v);
}

// ---------------------------------------------------------------------------
// self+nbr terms for node GEMM1:
//   s1s[p] = h_V[p] @ W1[:,0:128]^T      (self columns)
//   s1n[p] = h_V[p] @ W1[:,256:384]^T    (neighbor columns; gathered later)
// ---------------------------------------------------------------------------
__global__ __launch_bounds__(256) void self_gemm(
    const float* __restrict__ hv, const unsigned short* __restrict__ wsbf,
    float* __restrict__ s1s, float* __restrict__ s1n) {
    __shared__ __align__(16) unsigned short sA[32 * YS];
    const int tid = threadIdx.x;
    const int p0 = blockIdx.x * 32;
    const unsigned short* W1bf = wsbf + OFF_W1;
    for (int i = tid; i < 1024; i += 256) {
        int r = i >> 5, c4 = (i & 31) << 2;
        float4 v = *(const float4*)(hv + (size_t)(p0 + r) * Hn + c4);
        st_bf4(sA + r * YS + c4, v);
    }
    __syncthreads();
    const int wid = tid >> 6, lane = tid & 63;
    const int lane31 = lane & 31, lk = (lane >> 5) << 3;
    fx16 accS = {}, accN = {};
    const unsigned short* a   = sA + lane31 * YS + lk;
    const unsigned short* bwS = W1bf + (size_t)(32 * wid + lane31) * 384 + lk;        // cols 0..127
    const unsigned short* bwN = bwS + 256;                                            // cols 256..383
    #pragma unroll
    for (int ks = 0; ks < 8; ks++) {
        bh8 av = *(const bh8*)(a + ks * 16);
        accS = mfma_bf16(av, *(const bh8*)(bwS + ks * 16), accS);
        accN = mfma_bf16(av, *(const bh8*)(bwN + ks * 16), accN);
    }
    int col = 32 * wid + lane31;
    #pragma unroll
    for (int r = 0; r < 16; r++) {
        int row = (r & 3) + 8 * (r >> 2) + 4 * (lane >> 5);
        s1s[(size_t)(p0 + row) * Hn + col] = accS[r];
        s1n[(size_t)(p0 + row) * Hn + col] = accN[r];
    }
}

// ---------------------------------------------------------------------------
// Kernel A: node message MLP, GEMM3 eliminated by linearity:
//   z[node] = sum_k mask_k * gelu(Y2_k)   (reduced in GEMM2's epilogue)
// dh is finished as z@W3^T in node_fin_ffn. 2 GEMMs, 3 barriers.
// ---------------------------------------------------------------------------
__global__ __launch_bounds__(256, 4) void node_msg_mfma(
    const float* __restrict__ h_E, const int* __restrict__ E_idx,
    const float* __restrict__ mask_attend,
    const unsigned short* __restrict__ wsbf,
    const float* __restrict__ s1s, const float* __restrict__ s1n,
    const float* __restrict__ W1_b, const float* __restrict__ W2_b,
    unsigned short* __restrict__ zbf, float* __restrict__ zm) {
    __shared__ __align__(16) unsigned short sX[64 * YS]; // h_E; fp32 scratch after GEMM1
    __shared__ __align__(16) unsigned short sY[64 * YS];
    __shared__ float sS1[256];
    __shared__ float sMask[64];
    __shared__ int   sIdx[64];

    const int tid = threadIdx.x;
    const int p0 = blockIdx.x * 2;
    const int bB = p0 >> 11;
    const unsigned short* W1bf = wsbf + OFF_W1;
    const unsigned short* W2bf = wsbf + OFF_W2;

    // ---- staging: h_E only ----
    for (int i = tid; i < 1920; i += 256) {
        int r = i >> 5, c4 = (i & 31) << 2;
        float4 v = *(const float4*)(h_E + ((size_t)(p0 * Kn + r)) * Hn + c4);
        st_bf4(sX + r * YS + c4, v);
    }
    for (int i = tid; i < 272; i += 256)             // zero pad rows 60..63
        ((unsigned int*)(sX + 60 * YS))[i] = 0;
    if (tid < 64) {
        int g = tid >> 5, c4 = (tid & 31) << 2;
        *(float4*)(sS1 + g * 128 + c4) = *(const float4*)(s1s + (size_t)(p0 + g) * Hn + c4);
    }
    if (tid < 60) sMask[tid] = mask_attend[p0 * Kn + tid];
    if (tid < 64) sIdx[tid] = (tid < 60) ? E_idx[p0 * Kn + tid] : 0;
    __syncthreads();

    const int wid = tid >> 6, lane = tid & 63;
    const int mt = wid & 1, np = wid >> 1;
    const int lane31 = lane & 31, lk = (lane >> 5) << 3;
    const int rowBase = 32 * mt;
    const fx16 zv = {};
    const int c0 = 64 * np + lane31, c1 = c0 + 32;

    // ---- prefetch gathered neighbor term (s1n, L2-resident) into regs ----
    float pre0[16], pre1[16];
    #pragma unroll
    for (int r = 0; r < 16; r++) {
        int row = rowBase + 4 * (lane >> 5) + (r & 3) + 8 * (r >> 2);
        const float* sp = s1n + (size_t)(bB * NB + sIdx[row]) * Hn;
        pre0[r] = sp[c0];
        pre1[r] = sp[c1];
    }

    // ---- GEMM1: X[64,128] @ W1[:,128:256]^T + s1s + s1n + b -> GELU -> Y ----
    fx16 acc0 = zv, acc1 = zv;
    gemm_pair<8>(sX + (rowBase + lane31) * YS + lk,
                 W1bf + (64 * np + lane31) * 384 + 128 + lk,
                 W1bf + (64 * np + 32 + lane31) * 384 + 128 + lk, acc0, acc1);
    epi_gelu_sp(acc0, c0, rowBase, W1_b[c0], sS1, pre0, sY, lane);
    epi_gelu_sp(acc1, c1, rowBase, W1_b[c1], sS1, pre1, sY, lane);
    __syncthreads();

    // ---- GEMM2 + fused gelu + masked k-reduction (no GEMM3) ----
    acc0 = zv; acc1 = zv;
    gemm_pair<8>(sY + (rowBase + lane31) * YS + lk,
                 W2bf + (64 * np + lane31) * 128 + lk,
                 W2bf + (64 * np + 32 + lane31) * 128 + lk, acc0, acc1);
    float* fbuf = (float*)sX;                        // sX dead after GEMM1
    #pragma unroll
    for (int t = 0; t < 2; t++) {
        const fx16& ac = t ? acc1 : acc0;
        int col = t ? c1 : c0;
        float bias = W2_b[col];
        float sA0 = 0.f, sA1 = 0.f;
        #pragma unroll
        for (int r = 0; r < 16; r++) {
            int row = rowBase + (r & 3) + 8 * (r >> 2) + 4 * (lane >> 5);
            if (row < 60) {
                float v = gelu_f(ac[r] + bias) * sMask[row];
                if (row < Kn) sA0 += v; else sA1 += v;
            }
        }
        sA0 += __shfl_down(sA0, 32);
        sA1 += __shfl_down(sA1, 32);
        if (lane < 32) { fbuf[mt * 256 + col] = sA0; fbuf[mt * 256 + 128 + col] = sA1; }
    }
    __syncthreads();

    // ---- combine cross-wave partials, write z (bf16, pre-scaled by 1/30) ----
    {
        int g = tid >> 7, c = tid & 127;
        float zval = (fbuf[g * 128 + c] + fbuf[256 + g * 128 + c]) * (1.0f / 30.0f);
        zbf[(size_t)(p0 + g) * Hn + c] = f2bf(zval);
    }
    if (tid < 2) {
        float s = 0.f;
        #pragma unroll
        for (int k = 0; k < 30; k++) s += sMask[tid * 30 + k];
        zm[p0 + tid] = s * (1.0f / 30.0f);
    }
}

// ---------------------------------------------------------------------------
// Kernel B: dh = z@W3^T + zm*b3; LN1 (+h_V residual); FFN; LN2 + mask_V;
// then s11s/s11n = hV_out @ W11{self,nbr}^T. hmid never touches HBM.
// ---------------------------------------------------------------------------
__global__ __launch_bounds__(256) void node_fin_ffn(
    const unsigned short* __restrict__ zbf, const float* __restrict__ zm,
    const float* __restrict__ h_V, const float* __restrict__ mask_V,
    const unsigned short* __restrict__ wsbf,
    const float* __restrict__ W3_b, const float* __restrict__ Win_b,
    const float* __restrict__ Wout_b,
    const float* __restrict__ g1v, const float* __restrict__ b1v,
    const float* __restrict__ g2v, const float* __restrict__ b2v,
    float* __restrict__ hV_out, float* __restrict__ s11s, float* __restrict__ s11n) {
    __shared__ __align__(16) unsigned short sA[32 * YS];  // z bf16, then hmid bf16
    __shared__ __align__(16) unsigned short sH[32 * YS];  // hidden chunk bf16
    __shared__ __align__(16) float sO[32 * 132];          // dh fp32, then FFN-out fp32
    __shared__ __align__(16) float sM[32 * 132];          // hmid fp32
    __shared__ __align__(16) unsigned short sV[32 * YS];  // hV_out bf16 for s11
    __shared__ float sZm[32];

    const int tid = threadIdx.x;
    const int p0 = blockIdx.x * 32;
    const unsigned short* W3bf   = wsbf + OFF_W3;
    const unsigned short* Winbf  = wsbf + OFF_WIN;
    const unsigned short* Woutbf = wsbf + OFF_WOUT;
    const unsigned short* W11bf  = wsbf + OFF_W11;

    for (int i = tid; i < 512; i += 256) {
        int r = i >> 4, c8 = (i & 15) << 3;
        *(bh8*)(sA + r * YS + c8) = *(const bh8*)(zbf + (size_t)(p0 + r) * Hn + c8);
    }
    if (tid < 32) sZm[tid] = zm[p0 + tid];
    __syncthreads();

    const int wid = tid >> 6, lane = tid & 63;
    const int lane31 = lane & 31, lk = (lane >> 5) << 3;
    const fx16 zv = {};

    // ---- dh GEMM: z[32,128] @ W3^T ----
    {
        fx16 acc = zv;
        const unsigned short* a  = sA + lane31 * YS + lk;
        const unsigned short* bw = W3bf + (size_t)(32 * wid + lane31) * 128 + lk;
        #pragma unroll
        for (int ks = 0; ks < 8; ks++)
            acc = mfma_bf16(*(const bh8*)(a + ks * 16), *(const bh8*)(bw + ks * 16), acc);
        int col = 32 * wid + lane31;
        float bias = W3_b[col];
        #pragma unroll
        for (int r = 0; r < 16; r++) {
            int row = (r & 3) + 8 * (r >> 2) + 4 * (lane >> 5);
            sO[row * 132 + col] = acc[r] + sZm[row] * bias;
        }
    }
    __syncthreads();

    // ---- LN1: x = h_V + dh -> hmid (sM fp32 + sA bf16) ----
    for (int r = wid; r < 32; r += 4) {
        float x0 = sO[r * 132 + lane]      + h_V[(size_t)(p0 + r) * Hn + lane];
        float x1 = sO[r * 132 + 64 + lane] + h_V[(size_t)(p0 + r) * Hn + 64 + lane];
        float s = x0 + x1, q = x0 * x0 + x1 * x1;
        #pragma unroll
        for (int off = 32; off; off >>= 1) { s += __shfl_down(s, off); q += __shfl_down(q, off); }
        s = __shfl(s, 0); q = __shfl(q, 0);
        float mean = s * 0.0078125f;
        float rstd = rsqrtf(q * 0.0078125f - mean * mean + 1e-5f);
        float m0 = (x0 - mean) * rstd * g1v[lane]      + b1v[lane];
        float m1 = (x1 - mean) * rstd * g1v[lane + 64] + b1v[lane + 64];
        sM[r * 132 + lane]      = m0;
        sM[r * 132 + 64 + lane] = m1;
        sA[r * YS + lane]      = f2bf(m0);
        sA[r * YS + 64 + lane] = f2bf(m1);
    }
    __syncthreads();

    // ---- FFN ----
    fx16 accO = zv;
    for (int c = 0; c < 4; c++) {
        int hcol = 128 * c + 32 * wid + lane31;
        fx16 t = zv;
        {
            const unsigned short* a  = sA + lane31 * YS + lk;
            const unsigned short* bw = Winbf + (size_t)hcol * 128 + lk;
            #pragma unroll
            for (int ks = 0; ks < 8; ks++)
                t = mfma_bf16(*(const bh8*)(a + ks * 16), *(const bh8*)(bw + ks * 16), t);
        }
        float bias = Win_b[hcol];
        int colL = 32 * wid + lane31;
        #pragma unroll
        for (int r = 0; r < 16; r++) {
            int row = (r & 3) + 8 * (r >> 2) + 4 * (lane >> 5);
            sH[row * YS + colL] = f2bf(gelu_f(t[r] + bias));
        }
        __syncthreads();
        {
            const unsigned short* a  = sH + lane31 * YS + lk;
            const unsigned short* bw = Woutbf + (size_t)(32 * wid + lane31) * 512 + 128 * c + lk;
            #pragma unroll
            for (int ks = 0; ks < 8; ks++)
                accO = mfma_bf16(*(const bh8*)(a + ks * 16), *(const bh8*)(bw + ks * 16), accO);
        }
        __syncthreads();
    }
    {
        int col = 32 * wid + lane31;
        float bias = Wout_b[col];
        #pragma unroll
        for (int r = 0; r < 16; r++) {
            int row = (r & 3) + 8 * (r >> 2) + 4 * (lane >> 5);
            sO[row * 132 + col] = accO[r] + bias;
        }
    }
    __syncthreads();

    // ---- LN2 + mask_V -> hV_out, sV ----
    for (int r = wid; r < 32; r += 4) {
        float x0 = sO[r * 132 + lane]      + sM[r * 132 + lane];
        float x1 = sO[r * 132 + 64 + lane] + sM[r * 132 + 64 + lane];
        float s = x0 + x1, q = x0 * x0 + x1 * x1;
        #pragma unroll
        for (int off = 32; off; off >>= 1) { s += __shfl_down(s, off); q += __shfl_down(q, off); }
        s = __shfl(s, 0); q = __shfl(q, 0);
        float mean = s * 0.0078125f;
        float rstd = rsqrtf(q * 0.0078125f - mean * mean + 1e-5f);
        float mv = mask_V[p0 + r];
        float y0 = ((x0 - mean) * rstd * g2v[lane]      + b2v[lane])      * mv;
        float y1 = ((x1 - mean) * rstd * g2v[lane + 64] + b2v[lane + 64]) * mv;
        hV_out[(size_t)(p0 + r) * Hn + lane]      = y0;
        hV_out[(size_t)(p0 + r) * Hn + 64 + lane] = y1;
        sV[r * YS + lane]      = f2bf(y0);
        sV[r * YS + 64 + lane] = f2bf(y1);
    }
    __syncthreads();

    // ---- s11s/s11n = hV_out @ W11{self,nbr}^T ----
    {
        int col = 32 * wid + lane31;
        fx16 accS = zv, accN = zv;
        const unsigned short* a   = sV + lane31 * YS + lk;
        const unsigned short* bwS = W11bf + (size_t)col * 384 + lk;        // self cols 0..127
        const unsigned short* bwN = W11bf + (size_t)col * 384 + 256 + lk;  // nbr  cols 256..383
        #pragma unroll
        for (int ks = 0; ks < 8; ks++) {
            bh8 av = *(const bh8*)(a + ks * 16);
            accS = mfma_bf16(av, *(const bh8*)(bwS + ks * 16), accS);
            accN = mfma_bf16(av, *(const bh8*)(bwN + ks * 16), accN);
        }
        #pragma unroll
        for (int r = 0; r < 16; r++) {
            int row = (r & 3) + 8 * (r >> 2) + 4 * (lane >> 5);
            s11s[(size_t)(p0 + row) * Hn + col] = accS[r];
            s11n[(size_t)(p0 + row) * Hn + col] = accN[r];
        }
    }
}

// ---------------------------------------------------------------------------
// Kernel C: edge update — R1-verified version (5 barriers, in-place sY,
// bf16 h_E residual from sX, per-wave serial LN).
// ---------------------------------------------------------------------------
__global__ __launch_bounds__(256, 4) void edge_update_mfma(
    const float* __restrict__ h_E, const int* __restrict__ E_idx,
    const unsigned short* __restrict__ wsbf,
    const float* __restrict__ s11s, const float* __restrict__ s11n,
    const float* __restrict__ W11_b, const float* __restrict__ W12_b,
    const float* __restrict__ W13_b,
    const float* __restrict__ g3v, const float* __restrict__ b3v,
    float* __restrict__ hE_out) {
    __shared__ __align__(16) unsigned short sX[64 * YS]; // h_E, live to end (residual)
    __shared__ __align__(16) unsigned short sY[64 * YS];
    __shared__ float sS11[256];
    __shared__ int   sIdx[64];

    const int tid = threadIdx.x;
    const int p0 = blockIdx.x * 2;
    const int bB = p0 >> 11;
    const unsigned short* W11bf = wsbf + OFF_W11;
    const unsigned short* W12bf = wsbf + OFF_W12;
    const unsigned short* W13bf = wsbf + OFF_W13;

    for (int i = tid; i < 1920; i += 256) {
        int r = i >> 5, c4 = (i & 31) << 2;
        float4 v = *(const float4*)(h_E + ((size_t)(p0 * Kn + r)) * Hn + c4);
        st_bf4(sX + r * YS + c4, v);
    }
    for (int i = tid; i < 272; i += 256)
        ((unsigned int*)(sX + 60 * YS))[i] = 0;
    if (tid < 64) {
        int g = tid >> 5, c4 = (tid & 31) << 2;
        *(float4*)(sS11 + g * 128 + c4) = *(const float4*)(s11s + (size_t)(p0 + g) * Hn + c4);
    }
    if (tid < 64) sIdx[tid] = (tid < 60) ? E_idx[p0 * Kn + tid] : 0;
    __syncthreads();

    const int wid = tid >> 6, lane = tid & 63;
    const int mt = wid & 1, np = wid >> 1;
    const int lane31 = lane & 31, lk = (lane >> 5) << 3;
    const int rowBase = 32 * mt;
    const fx16 zv = {};
    const int c0 = 64 * np + lane31, c1 = c0 + 32;

    // prefetch gathered neighbor term (s11n, L2-resident)
    float pre0[16], pre1[16];
    #pragma unroll
    for (int r = 0; r < 16; r++) {
        int row = rowBase + 4 * (lane >> 5) + (r & 3) + 8 * (r >> 2);
        const float* sp = s11n + (size_t)(bB * NB + sIdx[row]) * Hn;
        pre0[r] = sp[c0];
        pre1[r] = sp[c1];
    }

    fx16 acc0 = zv, acc1 = zv;
    gemm_pair<8>(sX + (rowBase + lane31) * YS + lk,
                 W11bf + (64 * np + lane31) * 384 + 128 + lk,
                 W11bf + (64 * np + 32 + lane31) * 384 + 128 + lk, acc0, acc1);
    epi_gelu_sp(acc0, c0, rowBase, W11_b[c0], sS11, pre0, sY, lane);
    epi_gelu_sp(acc1, c1, rowBase, W11_b[c1], sS11, pre1, sY, lane);
    __syncthreads();

    acc0 = zv; acc1 = zv;
    gemm_pair<8>(sY + (rowBase + lane31) * YS + lk,
                 W12bf + (64 * np + lane31) * 128 + lk,
                 W12bf + (64 * np + 32 + lane31) * 128 + lk, acc0, acc1);
    __syncthreads();
    epi_gelu(acc0, c0, rowBase, W12_b[c0], sY, lane);
    epi_gelu(acc1, c1, rowBase, W12_b[c1], sY, lane);
    __syncthreads();

    acc0 = zv; acc1 = zv;
    gemm_pair<8>(sY + (rowBase + lane31) * YS + lk,
                 W13bf + (64 * np + lane31) * 128 + lk,
                 W13bf + (64 * np + 32 + lane31) * 128 + lk, acc0, acc1);
    __syncthreads();
    epi_plain(acc0, c0, rowBase, W13_b[c0], sY, lane);
    epi_plain(acc1, c1, rowBase, W13_b[c1], sY, lane);
    __syncthreads();

    // per-edge-row LN over E=128 (residual from bf16 h_E in sX)
    for (int r = wid; r < 60; r += 4) {
        float x0 = bf2f(sX[r * YS + lane])      + bf2f(sY[r * YS + lane]);
        float x1 = bf2f(sX[r * YS + 64 + lane]) + bf2f(sY[r * YS + 64 + lane]);
        float s = x0 + x1, q = x0 * x0 + x1 * x1;
        #pragma unroll
        for (int off = 32; off; off >>= 1) { s += __shfl_down(s, off); q += __shfl_down(q, off); }
        s = __shfl(s, 0); q = __shfl(q, 0);
        float mean = s * 0.0078125f;
        float rstd = rsqrtf(q * 0.0078125f - mean * mean + 1e-5f);
        float* op = hE_out + ((size_t)(p0 * Kn + r)) * 128;
        op[lane]      = (x0 - mean) * rstd * g3v[lane]      + b3v[lane];
        op[lane + 64] = (x1 - mean) * rstd * g3v[lane + 64] + b3v[lane + 64];
    }
}

extern "C" void kernel_launch(void* const* d_in, const int* in_sizes, int n_in,
                              void* d_out, int out_size, void* d_ws, size_t ws_size,
                              hipStream_t stream) {
    const float* h_V         = (const float*)d_in[0];
    const float* h_E         = (const float*)d_in[1];
    const int*   E_idx       = (const int*)  d_in[2];
    const float* mask_V      = (const float*)d_in[3];
    const float* mask_attend = (const float*)d_in[4];
    const float* W1_w  = (const float*)d_in[5];
    const float* W1_b  = (const float*)d_in[6];
    const float* W2_w  = (const float*)d_in[7];
    const float* W2_b  = (const float*)d_in[8];
    const float* W3_w  = (const float*)d_in[9];
    const float* W3_b  = (const float*)d_in[10];
    const float* W11_w = (const float*)d_in[11];
    const float* W11_b = (const float*)d_in[12];
    const float* W12_w = (const float*)d_in[13];
    const float* W12_b = (const float*)d_in[14];
    const float* W13_w = (const float*)d_in[15];
    const float* W13_b = (const float*)d_in[16];
    const float* Win_w  = (const float*)d_in[17];
    const float* Win_b  = (const float*)d_in[18];
    const float* Wout_w = (const float*)d_in[19];
    const float* Wout_b = (const float*)d_in[20];
    const float* g1 = (const float*)d_in[21];
    const float* b1 = (const float*)d_in[22];
    const float* g2 = (const float*)d_in[23];
    const float* b2 = (const float*)d_in[24];
    const float* g3 = (const float*)d_in[25];
    const float* b3 = (const float*)d_in[26];

    float* out    = (float*)d_out;
    float* hV_out = out;                          // [B,N,H]
    float* hE_out = out + (size_t)4 * 2048 * 128; // [B,N,K,E]
    unsigned short* wsbf = (unsigned short*)d_ws;
    float* wsf = (float*)(wsbf + W_TOTAL);
    unsigned short* zbf = (unsigned short*)wsf;   // [8192,128] bf16
    float* zm = wsf + WS_ZM;                      // [8192] fp32
    float* sS = wsf + WS_SS;   // s1 self, then (after B) s11 self
    float* sN = wsf + WS_SN;   // s1 nbr,  then (after B) s11 nbr

    prep_weights<<<(W_TOTAL + 255) / 256, 256, 0, stream>>>(
        W1_w, W2_w, W3_w, W11_w, W12_w, W13_w, Win_w, Wout_w, wsbf);

    self_gemm<<<256, 256, 0, stream>>>(h_V, wsbf, sS, sN);

    node_msg_mfma<<<4096, 256, 0, stream>>>(
        h_E, E_idx, mask_attend, wsbf, sS, sN, W1_b, W2_b, zbf, zm);

    node_fin_ffn<<<256, 256, 0, stream>>>(
        zbf, zm, h_V, mask_V, wsbf, W3_b, Win_b, Wout_b,
        g1, b1, g2, b2, hV_out, sS, sN);

    edge_update_mfma<<<4096, 256, 0, stream>>>(
        h_E, E_idx, wsbf, sS, sN,
        W11_b, W12_b, W13_b, g3, b3, hE_out);
}

// Round 4
// 489.811 us; speedup vs baseline: 1.2816x; 1.0280x over previous
//
#include <hip/hip_runtime.h>
#include <math.h>

// Problem constants
#define Kn    30
#define Hn    128
#define NB    2048          // nodes per batch
#define YS    136           // row stride (128 + 8 pad): 17 16B-groups (odd) -> conflict-free b128

// ws layout: bf16 weights, then fp32 scratch
#define OFF_W1    0
#define OFF_W2    49152
#define OFF_W3    65536
#define OFF_W11   81920
#define OFF_W12   131072
#define OFF_W13   147456
#define OFF_WIN   163840
#define OFF_WOUT  229376
#define W_TOTAL   294912
// fp32 scratch offsets (in floats, relative to end of weight region)
#define WS_ZM     524288    // zm [8192] fp32 (z bf16 occupies [0,524288) floats)
#define WS_SS     1048576   // self-term: s1self, then (aliased) s11self
#define WS_SN     2097152   // nbr-term:  s1nbr,  then (aliased) s11nbr

typedef __attribute__((ext_vector_type(8)))  short bh8;
typedef __attribute__((ext_vector_type(4)))  short bh4;
typedef __attribute__((ext_vector_type(16))) float fx16;

__device__ __forceinline__ unsigned short f2bf(float f) {
    unsigned int u = __float_as_uint(f);
    u += 0x7fffu + ((u >> 16) & 1u);        // RNE
    return (unsigned short)(u >> 16);
}
__device__ __forceinline__ float bf2f(unsigned short h) {
    return __uint_as_float(((unsigned int)h) << 16);
}
// tanh-form GELU via v_exp_f32 (|err vs erf-GELU| <~1e-3) — R1-exact form
__device__ __forceinline__ float gelu_f(float x) {
    float u = 0.7978845608028654f * x * (1.0f + 0.044715f * x * x);
    return x / (1.0f + __expf(-2.0f * u));
}
__device__ __forceinline__ fx16 mfma_bf16(bh8 a, bh8 b, fx16 c) {
    return __builtin_amdgcn_mfma_f32_32x32x16_bf16(a, b, c, 0, 0, 0);
}
__device__ __forceinline__ void st_bf4(unsigned short* dst, float4 v) {
    bh4 t;
    t.x = (short)f2bf(v.x); t.y = (short)f2bf(v.y);
    t.z = (short)f2bf(v.z); t.w = (short)f2bf(v.w);
    *(bh4*)dst = t;                          // ds_write_b64
}

// Fully-unrolled K-loop, single B n-tile (8-wave mapping: 1 tile/wave).
template<int KS>
__device__ __forceinline__ void gemm_one(const unsigned short* __restrict__ aBase,
                                         const unsigned short* __restrict__ b0,
                                         fx16& acc0) {
    #pragma unroll
    for (int ks = 0; ks < KS; ks++) {
        bh8 a = *(const bh8*)(aBase + ks * 16);
        acc0 = mfma_bf16(a, *(const bh8*)(b0 + ks * 16), acc0);
    }
}

// C-layout (verified m74/m101): col = lane&31, row = (reg&3)+8*(reg>>2)+4*(lane>>5)
// epilogue with self-term (LDS) + prefetched nbr-term (regs) + bias + gelu
__device__ __forceinline__ void epi_gelu_sp(const fx16& ac, int col, int rowBase,
                                            float bias, const float* __restrict__ sSelf,
                                            const float* pre,
                                            unsigned short* __restrict__ dst, int lane) {
    int ro = rowBase + 4 * (lane >> 5);
    #pragma unroll
    for (int r = 0; r < 16; r++) {
        int row = ro + (r & 3) + 8 * (r >> 2);
        float st = sSelf[((row >= Kn) ? 128 : 0) + col];
        dst[row * YS + col] = f2bf(gelu_f(ac[r] + bias + st + pre[r]));
    }
}
__device__ __forceinline__ void epi_gelu(const fx16& ac, int col, int rowBase,
                                         float bias, unsigned short* __restrict__ dst,
                                         int lane) {
    int ro = rowBase + 4 * (lane >> 5);
    #pragma unroll
    for (int r = 0; r < 16; r++) {
        int row = ro + (r & 3) + 8 * (r >> 2);
        dst[row * YS + col] = f2bf(gelu_f(ac[r] + bias));
    }
}
__device__ __forceinline__ void epi_plain(const fx16& ac, int col, int rowBase,
                                          float bias, unsigned short* __restrict__ dst,
                                          int lane) {
    int ro = rowBase + 4 * (lane >> 5);
    #pragma unroll
    for (int r = 0; r < 16; r++) {
        int row = ro + (r & 3) + 8 * (r >> 2);
        dst[row * YS + col] = f2bf(ac[r] + bias);
    }
}

// ---------------------------------------------------------------------------
// prep: fp32 -> bf16 weights into workspace
// ---------------------------------------------------------------------------
__global__ __launch_bounds__(256) void prep_weights(
    const float* __restrict__ W1, const float* __restrict__ W2,
    const float* __restrict__ W3, const float* __restrict__ W11,
    const float* __restrict__ W12, const float* __restrict__ W13,
    const float* __restrict__ Win, const float* __restrict__ Wout,
    unsigned short* __restrict__ wsbf) {
    int i = blockIdx.x * 256 + threadIdx.x;
    if (i >= W_TOTAL) return;
    float v;
    if      (i < OFF_W2)   v = W1[i - OFF_W1];
    else if (i < OFF_W3)   v = W2[i - OFF_W2];
    else if (i < OFF_W11)  v = W3[i - OFF_W3];
    else if (i < OFF_W12)  v = W11[i - OFF_W11];
    else if (i < OFF_W13)  v = W12[i - OFF_W12];
    else if (i < OFF_WIN)  v = W13[i - OFF_W13];
    else if (i < OFF_WOUT) v = Win[i - OFF_WIN];
    else                   v = Wout[i - OFF_WOUT];
    wsbf[i] = f2bf(v);
}

// ---------------------------------------------------------------------------
// self+nbr terms for node GEMM1:
//   s1s[p] = h_V[p] @ W1[:,0:128]^T      (self columns)
//   s1n[p] = h_V[p] @ W1[:,256:384]^T    (neighbor columns; gathered later)
// ---------------------------------------------------------------------------
__global__ __launch_bounds__(256) void self_gemm(
    const float* __restrict__ hv, const unsigned short* __restrict__ wsbf,
    float* __restrict__ s1s, float* __restrict__ s1n) {
    __shared__ __align__(16) unsigned short sA[32 * YS];
    const int tid = threadIdx.x;
    const int p0 = blockIdx.x * 32;
    const unsigned short* W1bf = wsbf + OFF_W1;
    for (int i = tid; i < 1024; i += 256) {
        int r = i >> 5, c4 = (i & 31) << 2;
        float4 v = *(const float4*)(hv + (size_t)(p0 + r) * Hn + c4);
        st_bf4(sA + r * YS + c4, v);
    }
    __syncthreads();
    const int wid = tid >> 6, lane = tid & 63;
    const int lane31 = lane & 31, lk = (lane >> 5) << 3;
    fx16 accS = {}, accN = {};
    const unsigned short* a   = sA + lane31 * YS + lk;
    const unsigned short* bwS = W1bf + (size_t)(32 * wid + lane31) * 384 + lk;        // cols 0..127
    const unsigned short* bwN = bwS + 256;                                            // cols 256..383
    #pragma unroll
    for (int ks = 0; ks < 8; ks++) {
        bh8 av = *(const bh8*)(a + ks * 16);
        accS = mfma_bf16(av, *(const bh8*)(bwS + ks * 16), accS);
        accN = mfma_bf16(av, *(const bh8*)(bwN + ks * 16), accN);
    }
    int col = 32 * wid + lane31;
    #pragma unroll
    for (int r = 0; r < 16; r++) {
        int row = (r & 3) + 8 * (r >> 2) + 4 * (lane >> 5);
        s1s[(size_t)(p0 + row) * Hn + col] = accS[r];
        s1n[(size_t)(p0 + row) * Hn + col] = accN[r];
    }
}

// ---------------------------------------------------------------------------
// Kernel A: node message MLP (8 waves, 512 thr). Each wave: one 32-row x
// 32-col output tile (mt=wid&1 row-half, ct=wid>>1 col-quarter).
// z[node] = sum_k mask_k * gelu(Y2_k); dh finished as z@W3^T in kernel B.
// LDS ~36.5 KB -> 4 blocks/CU -> 32 waves/CU.
// ---------------------------------------------------------------------------
__global__ __launch_bounds__(512, 8) void node_msg_mfma(
    const float* __restrict__ h_E, const int* __restrict__ E_idx,
    const float* __restrict__ mask_attend,
    const unsigned short* __restrict__ wsbf,
    const float* __restrict__ s1s, const float* __restrict__ s1n,
    const float* __restrict__ W1_b, const float* __restrict__ W2_b,
    unsigned short* __restrict__ zbf, float* __restrict__ zm) {
    __shared__ __align__(16) unsigned short sX[64 * YS]; // h_E; fp32 scratch after GEMM1
    __shared__ __align__(16) unsigned short sY[64 * YS];
    __shared__ float sS1[256];
    __shared__ float sMask[64];
    __shared__ int   sIdx[64];

    const int tid = threadIdx.x;
    const int p0 = blockIdx.x * 2;
    const int bB = p0 >> 11;
    const unsigned short* W1bf = wsbf + OFF_W1;
    const unsigned short* W2bf = wsbf + OFF_W2;

    // ---- staging: h_E only ----
    for (int i = tid; i < 1920; i += 512) {
        int r = i >> 5, c4 = (i & 31) << 2;
        float4 v = *(const float4*)(h_E + ((size_t)(p0 * Kn + r)) * Hn + c4);
        st_bf4(sX + r * YS + c4, v);
    }
    if (tid < 272)                                   // zero pad rows 60..63
        ((unsigned int*)(sX + 60 * YS))[tid] = 0;
    if (tid < 64) {
        int g = tid >> 5, c4 = (tid & 31) << 2;
        *(float4*)(sS1 + g * 128 + c4) = *(const float4*)(s1s + (size_t)(p0 + g) * Hn + c4);
    }
    if (tid < 60) sMask[tid] = mask_attend[p0 * Kn + tid];
    if (tid < 64) sIdx[tid] = (tid < 60) ? E_idx[p0 * Kn + tid] : 0;
    __syncthreads();

    const int wid = tid >> 6, lane = tid & 63;
    const int mt = wid & 1, ct = wid >> 1;
    const int lane31 = lane & 31, lk = (lane >> 5) << 3;
    const int rowBase = 32 * mt;
    const fx16 zv = {};
    const int col = 32 * ct + lane31;

    // ---- prefetch gathered neighbor term (s1n, L2-resident) into regs ----
    float pre[16];
    #pragma unroll
    for (int r = 0; r < 16; r++) {
        int row = rowBase + 4 * (lane >> 5) + (r & 3) + 8 * (r >> 2);
        pre[r] = s1n[(size_t)(bB * NB + sIdx[row]) * Hn + col];
    }

    // ---- GEMM1: X[64,128] @ W1[:,128:256]^T + s1s + s1n + b -> GELU -> Y ----
    fx16 acc = zv;
    gemm_one<8>(sX + (rowBase + lane31) * YS + lk,
                W1bf + (size_t)col * 384 + 128 + lk, acc);
    epi_gelu_sp(acc, col, rowBase, W1_b[col], sS1, pre, sY, lane);
    __syncthreads();

    // ---- GEMM2 + fused gelu + masked k-reduction (no GEMM3) ----
    acc = zv;
    gemm_one<8>(sY + (rowBase + lane31) * YS + lk,
                W2bf + (size_t)col * 128 + lk, acc);
    float* fbuf = (float*)sX;                        // sX dead after GEMM1
    {
        float bias = W2_b[col];
        float sA0 = 0.f, sA1 = 0.f;
        #pragma unroll
        for (int r = 0; r < 16; r++) {
            int row = rowBase + (r & 3) + 8 * (r >> 2) + 4 * (lane >> 5);
            if (row < 60) {
                float v = gelu_f(acc[r] + bias) * sMask[row];
                if (row < Kn) sA0 += v; else sA1 += v;
            }
        }
        sA0 += __shfl_down(sA0, 32);
        sA1 += __shfl_down(sA1, 32);
        if (lane < 32) { fbuf[mt * 256 + col] = sA0; fbuf[mt * 256 + 128 + col] = sA1; }
    }
    __syncthreads();

    // ---- combine cross-wave partials, write z (bf16, pre-scaled by 1/30) ----
    if (tid < 256) {
        int g = tid >> 7, c = tid & 127;
        float zval = (fbuf[g * 128 + c] + fbuf[256 + g * 128 + c]) * (1.0f / 30.0f);
        zbf[(size_t)(p0 + g) * Hn + c] = f2bf(zval);
    }
    if (tid < 2) {
        float s = 0.f;
        #pragma unroll
        for (int k = 0; k < 30; k++) s += sMask[tid * 30 + k];
        zm[p0 + tid] = s * (1.0f / 30.0f);
    }
}

// ---------------------------------------------------------------------------
// Kernel B: dh = z@W3^T + zm*b3; LN1 (+h_V residual); FFN; LN2 + mask_V;
// then s11s/s11n = hV_out @ W11{self,nbr}^T. hmid never touches HBM.
// ---------------------------------------------------------------------------
__global__ __launch_bounds__(256) void node_fin_ffn(
    const unsigned short* __restrict__ zbf, const float* __restrict__ zm,
    const float* __restrict__ h_V, const float* __restrict__ mask_V,
    const unsigned short* __restrict__ wsbf,
    const float* __restrict__ W3_b, const float* __restrict__ Win_b,
    const float* __restrict__ Wout_b,
    const float* __restrict__ g1v, const float* __restrict__ b1v,
    const float* __restrict__ g2v, const float* __restrict__ b2v,
    float* __restrict__ hV_out, float* __restrict__ s11s, float* __restrict__ s11n) {
    __shared__ __align__(16) unsigned short sA[32 * YS];  // z bf16, then hmid bf16
    __shared__ __align__(16) unsigned short sH[32 * YS];  // hidden chunk bf16
    __shared__ __align__(16) float sO[32 * 132];          // dh fp32, then FFN-out fp32
    __shared__ __align__(16) float sM[32 * 132];          // hmid fp32
    __shared__ __align__(16) unsigned short sV[32 * YS];  // hV_out bf16 for s11
    __shared__ float sZm[32];

    const int tid = threadIdx.x;
    const int p0 = blockIdx.x * 32;
    const unsigned short* W3bf   = wsbf + OFF_W3;
    const unsigned short* Winbf  = wsbf + OFF_WIN;
    const unsigned short* Woutbf = wsbf + OFF_WOUT;
    const unsigned short* W11bf  = wsbf + OFF_W11;

    for (int i = tid; i < 512; i += 256) {
        int r = i >> 4, c8 = (i & 15) << 3;
        *(bh8*)(sA + r * YS + c8) = *(const bh8*)(zbf + (size_t)(p0 + r) * Hn + c8);
    }
    if (tid < 32) sZm[tid] = zm[p0 + tid];
    __syncthreads();

    const int wid = tid >> 6, lane = tid & 63;
    const int lane31 = lane & 31, lk = (lane >> 5) << 3;
    const fx16 zv = {};

    // ---- dh GEMM: z[32,128] @ W3^T ----
    {
        fx16 acc = zv;
        const unsigned short* a  = sA + lane31 * YS + lk;
        const unsigned short* bw = W3bf + (size_t)(32 * wid + lane31) * 128 + lk;
        #pragma unroll
        for (int ks = 0; ks < 8; ks++)
            acc = mfma_bf16(*(const bh8*)(a + ks * 16), *(const bh8*)(bw + ks * 16), acc);
        int col = 32 * wid + lane31;
        float bias = W3_b[col];
        #pragma unroll
        for (int r = 0; r < 16; r++) {
            int row = (r & 3) + 8 * (r >> 2) + 4 * (lane >> 5);
            sO[row * 132 + col] = acc[r] + sZm[row] * bias;
        }
    }
    __syncthreads();

    // ---- LN1: x = h_V + dh -> hmid (sM fp32 + sA bf16) ----
    for (int r = wid; r < 32; r += 4) {
        float x0 = sO[r * 132 + lane]      + h_V[(size_t)(p0 + r) * Hn + lane];
        float x1 = sO[r * 132 + 64 + lane] + h_V[(size_t)(p0 + r) * Hn + 64 + lane];
        float s = x0 + x1, q = x0 * x0 + x1 * x1;
        #pragma unroll
        for (int off = 32; off; off >>= 1) { s += __shfl_down(s, off); q += __shfl_down(q, off); }
        s = __shfl(s, 0); q = __shfl(q, 0);
        float mean = s * 0.0078125f;
        float rstd = rsqrtf(q * 0.0078125f - mean * mean + 1e-5f);
        float m0 = (x0 - mean) * rstd * g1v[lane]      + b1v[lane];
        float m1 = (x1 - mean) * rstd * g1v[lane + 64] + b1v[lane + 64];
        sM[r * 132 + lane]      = m0;
        sM[r * 132 + 64 + lane] = m1;
        sA[r * YS + lane]      = f2bf(m0);
        sA[r * YS + 64 + lane] = f2bf(m1);
    }
    __syncthreads();

    // ---- FFN ----
    fx16 accO = zv;
    for (int c = 0; c < 4; c++) {
        int hcol = 128 * c + 32 * wid + lane31;
        fx16 t = zv;
        {
            const unsigned short* a  = sA + lane31 * YS + lk;
            const unsigned short* bw = Winbf + (size_t)hcol * 128 + lk;
            #pragma unroll
            for (int ks = 0; ks < 8; ks++)
                t = mfma_bf16(*(const bh8*)(a + ks * 16), *(const bh8*)(bw + ks * 16), t);
        }
        float bias = Win_b[hcol];
        int colL = 32 * wid + lane31;
        #pragma unroll
        for (int r = 0; r < 16; r++) {
            int row = (r & 3) + 8 * (r >> 2) + 4 * (lane >> 5);
            sH[row * YS + colL] = f2bf(gelu_f(t[r] + bias));
        }
        __syncthreads();
        {
            const unsigned short* a  = sH + lane31 * YS + lk;
            const unsigned short* bw = Woutbf + (size_t)(32 * wid + lane31) * 512 + 128 * c + lk;
            #pragma unroll
            for (int ks = 0; ks < 8; ks++)
                accO = mfma_bf16(*(const bh8*)(a + ks * 16), *(const bh8*)(bw + ks * 16), accO);
        }
        __syncthreads();
    }
    {
        int col = 32 * wid + lane31;
        float bias = Wout_b[col];
        #pragma unroll
        for (int r = 0; r < 16; r++) {
            int row = (r & 3) + 8 * (r >> 2) + 4 * (lane >> 5);
            sO[row * 132 + col] = accO[r] + bias;
        }
    }
    __syncthreads();

    // ---- LN2 + mask_V -> hV_out, sV ----
    for (int r = wid; r < 32; r += 4) {
        float x0 = sO[r * 132 + lane]      + sM[r * 132 + lane];
        float x1 = sO[r * 132 + 64 + lane] + sM[r * 132 + 64 + lane];
        float s = x0 + x1, q = x0 * x0 + x1 * x1;
        #pragma unroll
        for (int off = 32; off; off >>= 1) { s += __shfl_down(s, off); q += __shfl_down(q, off); }
        s = __shfl(s, 0); q = __shfl(q, 0);
        float mean = s * 0.0078125f;
        float rstd = rsqrtf(q * 0.0078125f - mean * mean + 1e-5f);
        float mv = mask_V[p0 + r];
        float y0 = ((x0 - mean) * rstd * g2v[lane]      + b2v[lane])      * mv;
        float y1 = ((x1 - mean) * rstd * g2v[lane + 64] + b2v[lane + 64]) * mv;
        hV_out[(size_t)(p0 + r) * Hn + lane]      = y0;
        hV_out[(size_t)(p0 + r) * Hn + 64 + lane] = y1;
        sV[r * YS + lane]      = f2bf(y0);
        sV[r * YS + 64 + lane] = f2bf(y1);
    }
    __syncthreads();

    // ---- s11s/s11n = hV_out @ W11{self,nbr}^T ----
    {
        int col = 32 * wid + lane31;
        fx16 accS = zv, accN = zv;
        const unsigned short* a   = sV + lane31 * YS + lk;
        const unsigned short* bwS = W11bf + (size_t)col * 384 + lk;        // self cols 0..127
        const unsigned short* bwN = W11bf + (size_t)col * 384 + 256 + lk;  // nbr  cols 256..383
        #pragma unroll
        for (int ks = 0; ks < 8; ks++) {
            bh8 av = *(const bh8*)(a + ks * 16);
            accS = mfma_bf16(av, *(const bh8*)(bwS + ks * 16), accS);
            accN = mfma_bf16(av, *(const bh8*)(bwN + ks * 16), accN);
        }
        #pragma unroll
        for (int r = 0; r < 16; r++) {
            int row = (r & 3) + 8 * (r >> 2) + 4 * (lane >> 5);
            s11s[(size_t)(p0 + row) * Hn + col] = accS[r];
            s11n[(size_t)(p0 + row) * Hn + col] = accN[r];
        }
    }
}

// ---------------------------------------------------------------------------
// Kernel C: edge update (8 waves, 512 thr) — R3-verified barrier structure,
// each wave one 32x32 output tile; serial LN split over 8 waves.
// ---------------------------------------------------------------------------
__global__ __launch_bounds__(512, 8) void edge_update_mfma(
    const float* __restrict__ h_E, const int* __restrict__ E_idx,
    const unsigned short* __restrict__ wsbf,
    const float* __restrict__ s11s, const float* __restrict__ s11n,
    const float* __restrict__ W11_b, const float* __restrict__ W12_b,
    const float* __restrict__ W13_b,
    const float* __restrict__ g3v, const float* __restrict__ b3v,
    float* __restrict__ hE_out) {
    __shared__ __align__(16) unsigned short sX[64 * YS]; // h_E, live to end (residual)
    __shared__ __align__(16) unsigned short sY[64 * YS];
    __shared__ float sS11[256];
    __shared__ int   sIdx[64];

    const int tid = threadIdx.x;
    const int p0 = blockIdx.x * 2;
    const int bB = p0 >> 11;
    const unsigned short* W11bf = wsbf + OFF_W11;
    const unsigned short* W12bf = wsbf + OFF_W12;
    const unsigned short* W13bf = wsbf + OFF_W13;

    for (int i = tid; i < 1920; i += 512) {
        int r = i >> 5, c4 = (i & 31) << 2;
        float4 v = *(const float4*)(h_E + ((size_t)(p0 * Kn + r)) * Hn + c4);
        st_bf4(sX + r * YS + c4, v);
    }
    if (tid < 272)
        ((unsigned int*)(sX + 60 * YS))[tid] = 0;
    if (tid < 64) {
        int g = tid >> 5, c4 = (tid & 31) << 2;
        *(float4*)(sS11 + g * 128 + c4) = *(const float4*)(s11s + (size_t)(p0 + g) * Hn + c4);
    }
    if (tid < 64) sIdx[tid] = (tid < 60) ? E_idx[p0 * Kn + tid] : 0;
    __syncthreads();

    const int wid = tid >> 6, lane = tid & 63;
    const int mt = wid & 1, ct = wid >> 1;
    const int lane31 = lane & 31, lk = (lane >> 5) << 3;
    const int rowBase = 32 * mt;
    const fx16 zv = {};
    const int col = 32 * ct + lane31;

    // prefetch gathered neighbor term (s11n, L2-resident)
    float pre[16];
    #pragma unroll
    for (int r = 0; r < 16; r++) {
        int row = rowBase + 4 * (lane >> 5) + (r & 3) + 8 * (r >> 2);
        pre[r] = s11n[(size_t)(bB * NB + sIdx[row]) * Hn + col];
    }

    fx16 acc = zv;
    gemm_one<8>(sX + (rowBase + lane31) * YS + lk,
                W11bf + (size_t)col * 384 + 128 + lk, acc);
    epi_gelu_sp(acc, col, rowBase, W11_b[col], sS11, pre, sY, lane);
    __syncthreads();

    acc = zv;
    gemm_one<8>(sY + (rowBase + lane31) * YS + lk,
                W12bf + (size_t)col * 128 + lk, acc);
    __syncthreads();
    epi_gelu(acc, col, rowBase, W12_b[col], sY, lane);
    __syncthreads();

    acc = zv;
    gemm_one<8>(sY + (rowBase + lane31) * YS + lk,
                W13bf + (size_t)col * 128 + lk, acc);
    __syncthreads();
    epi_plain(acc, col, rowBase, W13_b[col], sY, lane);
    __syncthreads();

    // per-edge-row LN over E=128 (residual from bf16 h_E in sX)
    for (int r = wid; r < 60; r += 8) {
        float x0 = bf2f(sX[r * YS + lane])      + bf2f(sY[r * YS + lane]);
        float x1 = bf2f(sX[r * YS + 64 + lane]) + bf2f(sY[r * YS + 64 + lane]);
        float s = x0 + x1, q = x0 * x0 + x1 * x1;
        #pragma unroll
        for (int off = 32; off; off >>= 1) { s += __shfl_down(s, off); q += __shfl_down(q, off); }
        s = __shfl(s, 0); q = __shfl(q, 0);
        float mean = s * 0.0078125f;
        float rstd = rsqrtf(q * 0.0078125f - mean * mean + 1e-5f);
        float* op = hE_out + ((size_t)(p0 * Kn + r)) * 128;
        op[lane]      = (x0 - mean) * rstd * g3v[lane]      + b3v[lane];
        op[lane + 64] = (x1 - mean) * rstd * g3v[lane + 64] + b3v[lane + 64];
    }
}

extern "C" void kernel_launch(void* const* d_in, const int* in_sizes, int n_in,
                              void* d_out, int out_size, void* d_ws, size_t ws_size,
                              hipStream_t stream) {
    const float* h_V         = (const float*)d_in[0];
    const float* h_E         = (const float*)d_in[1];
    const int*   E_idx       = (const int*)  d_in[2];
    const float* mask_V      = (const float*)d_in[3];
    const float* mask_attend = (const float*)d_in[4];
    const float* W1_w  = (const float*)d_in[5];
    const float* W1_b  = (const float*)d_in[6];
    const float* W2_w  = (const float*)d_in[7];
    const float* W2_b  = (const float*)d_in[8];
    const float* W3_w  = (const float*)d_in[9];
    const float* W3_b  = (const float*)d_in[10];
    const float* W11_w = (const float*)d_in[11];
    const float* W11_b = (const float*)d_in[12];
    const float* W12_w = (const float*)d_in[13];
    const float* W12_b = (const float*)d_in[14];
    const float* W13_w = (const float*)d_in[15];
    const float* W13_b = (const float*)d_in[16];
    const float* Win_w  = (const float*)d_in[17];
    const float* Win_b  = (const float*)d_in[18];
    const float* Wout_w = (const float*)d_in[19];
    const float* Wout_b = (const float*)d_in[20];
    const float* g1 = (const float*)d_in[21];
    const float* b1 = (const float*)d_in[22];
    const float* g2 = (const float*)d_in[23];
    const float* b2 = (const float*)d_in[24];
    const float* g3 = (const float*)d_in[25];
    const float* b3 = (const float*)d_in[26];

    float* out    = (float*)d_out;
    float* hV_out = out;                          // [B,N,H]
    float* hE_out = out + (size_t)4 * 2048 * 128; // [B,N,K,E]
    unsigned short* wsbf = (unsigned short*)d_ws;
    float* wsf = (float*)(wsbf + W_TOTAL);
    unsigned short* zbf = (unsigned short*)wsf;   // [8192,128] bf16
    float* zm = wsf + WS_ZM;                      // [8192] fp32
    float* sS = wsf + WS_SS;   // s1 self, then (after B) s11 self
    float* sN = wsf + WS_SN;   // s1 nbr,  then (after B) s11 nbr

    prep_weights<<<(W_TOTAL + 255) / 256, 256, 0, stream>>>(
        W1_w, W2_w, W3_w, W11_w, W12_w, W13_w, Win_w, Wout_w, wsbf);

    self_gemm<<<256, 256, 0, stream>>>(h_V, wsbf, sS, sN);

    node_msg_mfma<<<4096, 512, 0, stream>>>(
        h_E, E_idx, mask_attend, wsbf, sS, sN, W1_b, W2_b, zbf, zm);

    node_fin_ffn<<<256, 256, 0, stream>>>(
        zbf, zm, h_V, mask_V, wsbf, W3_b, Win_b, Wout_b,
        g1, b1, g2, b2, hV_out, sS, sN);

    edge_update_mfma<<<4096, 512, 0, stream>>>(
        h_E, E_idx, wsbf, sS, sN,
        W11_b, W12_b, W13_b, g3, b3, hE_out);
}

// Round 5
// 482.268 us; speedup vs baseline: 1.3017x; 1.0156x over previous
//
#include <hip/hip_runtime.h>
#include <math.h>

// Problem constants
#define Kn    30
#define Hn    128
#define NB    2048          // nodes per batch
#define YS    136           // row stride (128 + 8 pad): 17 16B-groups (odd) -> conflict-free b128

// ws layout: bf16 weights, then fp32 scratch
#define OFF_W1    0
#define OFF_W2    49152
#define OFF_W3    65536
#define OFF_W11   81920
#define OFF_W12   131072
#define OFF_W13   147456
#define OFF_WIN   163840
#define OFF_WOUT  229376
#define W_TOTAL   294912
// fp32 scratch offsets (in floats, relative to end of weight region)
#define WS_ZM     524288    // zm [8192] fp32 (z bf16 occupies [0,524288) floats)
#define WS_SS     1048576   // self-term: s1self, then (aliased) s11self
#define WS_SN     2097152   // nbr-term:  s1nbr,  then (aliased) s11nbr

typedef __attribute__((ext_vector_type(8)))  short bh8;
typedef __attribute__((ext_vector_type(4)))  short bh4;
typedef __attribute__((ext_vector_type(16))) float fx16;

__device__ __forceinline__ unsigned short f2bf(float f) {
    unsigned int u = __float_as_uint(f);
    u += 0x7fffu + ((u >> 16) & 1u);        // RNE
    return (unsigned short)(u >> 16);
}
__device__ __forceinline__ float bf2f(unsigned short h) {
    return __uint_as_float(((unsigned int)h) << 16);
}
// tanh-form GELU via v_exp_f32 (|err vs erf-GELU| <~1e-3) — R1-exact form
__device__ __forceinline__ float gelu_f(float x) {
    float u = 0.7978845608028654f * x * (1.0f + 0.044715f * x * x);
    return x / (1.0f + __expf(-2.0f * u));
}
__device__ __forceinline__ fx16 mfma_bf16(bh8 a, bh8 b, fx16 c) {
    return __builtin_amdgcn_mfma_f32_32x32x16_bf16(a, b, c, 0, 0, 0);
}
__device__ __forceinline__ void st_bf4(unsigned short* dst, float4 v) {
    bh4 t;
    t.x = (short)f2bf(v.x); t.y = (short)f2bf(v.y);
    t.z = (short)f2bf(v.z); t.w = (short)f2bf(v.w);
    *(bh4*)dst = t;                          // ds_write_b64
}

// Fully-unrolled K-loop, single B n-tile (8-wave mapping: 1 tile/wave).
template<int KS>
__device__ __forceinline__ void gemm_one(const unsigned short* __restrict__ aBase,
                                         const unsigned short* __restrict__ b0,
                                         fx16& acc0) {
    #pragma unroll
    for (int ks = 0; ks < KS; ks++) {
        bh8 a = *(const bh8*)(aBase + ks * 16);
        acc0 = mfma_bf16(a, *(const bh8*)(b0 + ks * 16), acc0);
    }
}

// C-layout (verified m74/m101): col = lane&31, row = (reg&3)+8*(reg>>2)+4*(lane>>5)
// epilogue with self-term (LDS) + DIRECT gathered nbr-term (global, L2-hit) + bias + gelu
// nbrCol = s?n + bB*NB*Hn + col; per-row address via sIdx (LDS). No long-lived
// prefetch regs -> fits the 64-VGPR budget at 8 waves/EU without spilling.
__device__ __forceinline__ void epi_gelu_sg(const fx16& ac, int col, int rowBase,
                                            float bias, const float* __restrict__ sSelf,
                                            const float* __restrict__ nbrCol,
                                            const int* __restrict__ sIdx,
                                            unsigned short* __restrict__ dst, int lane) {
    int ro = rowBase + 4 * (lane >> 5);
    #pragma unroll
    for (int r = 0; r < 16; r++) {
        int row = ro + (r & 3) + 8 * (r >> 2);
        float st = sSelf[((row >= Kn) ? 128 : 0) + col];
        float pn = nbrCol[(size_t)sIdx[row] * Hn];
        dst[row * YS + col] = f2bf(gelu_f(ac[r] + bias + st + pn));
    }
}
__device__ __forceinline__ void epi_gelu(const fx16& ac, int col, int rowBase,
                                         float bias, unsigned short* __restrict__ dst,
                                         int lane) {
    int ro = rowBase + 4 * (lane >> 5);
    #pragma unroll
    for (int r = 0; r < 16; r++) {
        int row = ro + (r & 3) + 8 * (r >> 2);
        dst[row * YS + col] = f2bf(gelu_f(ac[r] + bias));
    }
}
__device__ __forceinline__ void epi_plain(const fx16& ac, int col, int rowBase,
                                          float bias, unsigned short* __restrict__ dst,
                                          int lane) {
    int ro = rowBase + 4 * (lane >> 5);
    #pragma unroll
    for (int r = 0; r < 16; r++) {
        int row = ro + (r & 3) + 8 * (r >> 2);
        dst[row * YS + col] = f2bf(ac[r] + bias);
    }
}

// ---------------------------------------------------------------------------
// prep: fp32 -> bf16 weights into workspace
// ---------------------------------------------------------------------------
__global__ __launch_bounds__(256) void prep_weights(
    const float* __restrict__ W1, const float* __restrict__ W2,
    const float* __restrict__ W3, const float* __restrict__ W11,
    const float* __restrict__ W12, const float* __restrict__ W13,
    const float* __restrict__ Win, const float* __restrict__ Wout,
    unsigned short* __restrict__ wsbf) {
    int i = blockIdx.x * 256 + threadIdx.x;
    if (i >= W_TOTAL) return;
    float v;
    if      (i < OFF_W2)   v = W1[i - OFF_W1];
    else if (i < OFF_W3)   v = W2[i - OFF_W2];
    else if (i < OFF_W11)  v = W3[i - OFF_W3];
    else if (i < OFF_W12)  v = W11[i - OFF_W11];
    else if (i < OFF_W13)  v = W12[i - OFF_W12];
    else if (i < OFF_WIN)  v = W13[i - OFF_W13];
    else if (i < OFF_WOUT) v = Win[i - OFF_WIN];
    else                   v = Wout[i - OFF_WOUT];
    wsbf[i] = f2bf(v);
}

// ---------------------------------------------------------------------------
// self+nbr terms for node GEMM1:
//   s1s[p] = h_V[p] @ W1[:,0:128]^T      (self columns)
//   s1n[p] = h_V[p] @ W1[:,256:384]^T    (neighbor columns; gathered later)
// ---------------------------------------------------------------------------
__global__ __launch_bounds__(256) void self_gemm(
    const float* __restrict__ hv, const unsigned short* __restrict__ wsbf,
    float* __restrict__ s1s, float* __restrict__ s1n) {
    __shared__ __align__(16) unsigned short sA[32 * YS];
    const int tid = threadIdx.x;
    const int p0 = blockIdx.x * 32;
    const unsigned short* W1bf = wsbf + OFF_W1;
    for (int i = tid; i < 1024; i += 256) {
        int r = i >> 5, c4 = (i & 31) << 2;
        float4 v = *(const float4*)(hv + (size_t)(p0 + r) * Hn + c4);
        st_bf4(sA + r * YS + c4, v);
    }
    __syncthreads();
    const int wid = tid >> 6, lane = tid & 63;
    const int lane31 = lane & 31, lk = (lane >> 5) << 3;
    fx16 accS = {}, accN = {};
    const unsigned short* a   = sA + lane31 * YS + lk;
    const unsigned short* bwS = W1bf + (size_t)(32 * wid + lane31) * 384 + lk;        // cols 0..127
    const unsigned short* bwN = bwS + 256;                                            // cols 256..383
    #pragma unroll
    for (int ks = 0; ks < 8; ks++) {
        bh8 av = *(const bh8*)(a + ks * 16);
        accS = mfma_bf16(av, *(const bh8*)(bwS + ks * 16), accS);
        accN = mfma_bf16(av, *(const bh8*)(bwN + ks * 16), accN);
    }
    int col = 32 * wid + lane31;
    #pragma unroll
    for (int r = 0; r < 16; r++) {
        int row = (r & 3) + 8 * (r >> 2) + 4 * (lane >> 5);
        s1s[(size_t)(p0 + row) * Hn + col] = accS[r];
        s1n[(size_t)(p0 + row) * Hn + col] = accN[r];
    }
}

// ---------------------------------------------------------------------------
// Kernel A: node message MLP (8 waves, 512 thr). Each wave: one 32-row x
// 32-col output tile (mt=wid&1 row-half, ct=wid>>1 col-quarter).
// z[node] = sum_k mask_k * gelu(Y2_k); dh finished as z@W3^T in kernel B.
// Neighbor term gathered directly in GEMM1 epilogue (no prefetch regs).
// ---------------------------------------------------------------------------
__global__ __launch_bounds__(512, 8) void node_msg_mfma(
    const float* __restrict__ h_E, const int* __restrict__ E_idx,
    const float* __restrict__ mask_attend,
    const unsigned short* __restrict__ wsbf,
    const float* __restrict__ s1s, const float* __restrict__ s1n,
    const float* __restrict__ W1_b, const float* __restrict__ W2_b,
    unsigned short* __restrict__ zbf, float* __restrict__ zm) {
    __shared__ __align__(16) unsigned short sX[64 * YS]; // h_E; fp32 scratch after GEMM1
    __shared__ __align__(16) unsigned short sY[64 * YS];
    __shared__ float sS1[256];
    __shared__ float sMask[64];
    __shared__ int   sIdx[64];

    const int tid = threadIdx.x;
    const int p0 = blockIdx.x * 2;
    const int bB = p0 >> 11;
    const unsigned short* W1bf = wsbf + OFF_W1;
    const unsigned short* W2bf = wsbf + OFF_W2;

    // ---- staging: h_E only ----
    for (int i = tid; i < 1920; i += 512) {
        int r = i >> 5, c4 = (i & 31) << 2;
        float4 v = *(const float4*)(h_E + ((size_t)(p0 * Kn + r)) * Hn + c4);
        st_bf4(sX + r * YS + c4, v);
    }
    if (tid < 272)                                   // zero pad rows 60..63
        ((unsigned int*)(sX + 60 * YS))[tid] = 0;
    if (tid < 64) {
        int g = tid >> 5, c4 = (tid & 31) << 2;
        *(float4*)(sS1 + g * 128 + c4) = *(const float4*)(s1s + (size_t)(p0 + g) * Hn + c4);
    }
    if (tid < 60) sMask[tid] = mask_attend[p0 * Kn + tid];
    if (tid < 64) sIdx[tid] = (tid < 60) ? E_idx[p0 * Kn + tid] : 0;
    __syncthreads();

    const int wid = tid >> 6, lane = tid & 63;
    const int mt = wid & 1, ct = wid >> 1;
    const int lane31 = lane & 31, lk = (lane >> 5) << 3;
    const int rowBase = 32 * mt;
    const fx16 zv = {};
    const int col = 32 * ct + lane31;

    // ---- GEMM1: X[64,128] @ W1[:,128:256]^T + s1s + s1n(gathered) + b -> GELU -> Y ----
    fx16 acc = zv;
    gemm_one<8>(sX + (rowBase + lane31) * YS + lk,
                W1bf + (size_t)col * 384 + 128 + lk, acc);
    epi_gelu_sg(acc, col, rowBase, W1_b[col], sS1,
                s1n + (size_t)bB * NB * Hn + col, sIdx, sY, lane);
    __syncthreads();

    // ---- GEMM2 + fused gelu + masked k-reduction (no GEMM3) ----
    acc = zv;
    gemm_one<8>(sY + (rowBase + lane31) * YS + lk,
                W2bf + (size_t)col * 128 + lk, acc);
    float* fbuf = (float*)sX;                        // sX dead after GEMM1
    {
        float bias = W2_b[col];
        float sA0 = 0.f, sA1 = 0.f;
        #pragma unroll
        for (int r = 0; r < 16; r++) {
            int row = rowBase + (r & 3) + 8 * (r >> 2) + 4 * (lane >> 5);
            if (row < 60) {
                float v = gelu_f(acc[r] + bias) * sMask[row];
                if (row < Kn) sA0 += v; else sA1 += v;
            }
        }
        sA0 += __shfl_down(sA0, 32);
        sA1 += __shfl_down(sA1, 32);
        if (lane < 32) { fbuf[mt * 256 + col] = sA0; fbuf[mt * 256 + 128 + col] = sA1; }
    }
    __syncthreads();

    // ---- combine cross-wave partials, write z (bf16, pre-scaled by 1/30) ----
    if (tid < 256) {
        int g = tid >> 7, c = tid & 127;
        float zval = (fbuf[g * 128 + c] + fbuf[256 + g * 128 + c]) * (1.0f / 30.0f);
        zbf[(size_t)(p0 + g) * Hn + c] = f2bf(zval);
    }
    if (tid < 2) {
        float s = 0.f;
        #pragma unroll
        for (int k = 0; k < 30; k++) s += sMask[tid * 30 + k];
        zm[p0 + tid] = s * (1.0f / 30.0f);
    }
}

// ---------------------------------------------------------------------------
// Kernel B: dh = z@W3^T + zm*b3; LN1 (+h_V residual); FFN; LN2 + mask_V;
// then s11s/s11n = hV_out @ W11{self,nbr}^T. hmid never touches HBM.
// ---------------------------------------------------------------------------
__global__ __launch_bounds__(256) void node_fin_ffn(
    const unsigned short* __restrict__ zbf, const float* __restrict__ zm,
    const float* __restrict__ h_V, const float* __restrict__ mask_V,
    const unsigned short* __restrict__ wsbf,
    const float* __restrict__ W3_b, const float* __restrict__ Win_b,
    const float* __restrict__ Wout_b,
    const float* __restrict__ g1v, const float* __restrict__ b1v,
    const float* __restrict__ g2v, const float* __restrict__ b2v,
    float* __restrict__ hV_out, float* __restrict__ s11s, float* __restrict__ s11n) {
    __shared__ __align__(16) unsigned short sA[32 * YS];  // z bf16, then hmid bf16
    __shared__ __align__(16) unsigned short sH[32 * YS];  // hidden chunk bf16
    __shared__ __align__(16) float sO[32 * 132];          // dh fp32, then FFN-out fp32
    __shared__ __align__(16) float sM[32 * 132];          // hmid fp32
    __shared__ __align__(16) unsigned short sV[32 * YS];  // hV_out bf16 for s11
    __shared__ float sZm[32];

    const int tid = threadIdx.x;
    const int p0 = blockIdx.x * 32;
    const unsigned short* W3bf   = wsbf + OFF_W3;
    const unsigned short* Winbf  = wsbf + OFF_WIN;
    const unsigned short* Woutbf = wsbf + OFF_WOUT;
    const unsigned short* W11bf  = wsbf + OFF_W11;

    for (int i = tid; i < 512; i += 256) {
        int r = i >> 4, c8 = (i & 15) << 3;
        *(bh8*)(sA + r * YS + c8) = *(const bh8*)(zbf + (size_t)(p0 + r) * Hn + c8);
    }
    if (tid < 32) sZm[tid] = zm[p0 + tid];
    __syncthreads();

    const int wid = tid >> 6, lane = tid & 63;
    const int lane31 = lane & 31, lk = (lane >> 5) << 3;
    const fx16 zv = {};

    // ---- dh GEMM: z[32,128] @ W3^T ----
    {
        fx16 acc = zv;
        const unsigned short* a  = sA + lane31 * YS + lk;
        const unsigned short* bw = W3bf + (size_t)(32 * wid + lane31) * 128 + lk;
        #pragma unroll
        for (int ks = 0; ks < 8; ks++)
            acc = mfma_bf16(*(const bh8*)(a + ks * 16), *(const bh8*)(bw + ks * 16), acc);
        int col = 32 * wid + lane31;
        float bias = W3_b[col];
        #pragma unroll
        for (int r = 0; r < 16; r++) {
            int row = (r & 3) + 8 * (r >> 2) + 4 * (lane >> 5);
            sO[row * 132 + col] = acc[r] + sZm[row] * bias;
        }
    }
    __syncthreads();

    // ---- LN1: x = h_V + dh -> hmid (sM fp32 + sA bf16) ----
    for (int r = wid; r < 32; r += 4) {
        float x0 = sO[r * 132 + lane]      + h_V[(size_t)(p0 + r) * Hn + lane];
        float x1 = sO[r * 132 + 64 + lane] + h_V[(size_t)(p0 + r) * Hn + 64 + lane];
        float s = x0 + x1, q = x0 * x0 + x1 * x1;
        #pragma unroll
        for (int off = 32; off; off >>= 1) { s += __shfl_down(s, off); q += __shfl_down(q, off); }
        s = __shfl(s, 0); q = __shfl(q, 0);
        float mean = s * 0.0078125f;
        float rstd = rsqrtf(q * 0.0078125f - mean * mean + 1e-5f);
        float m0 = (x0 - mean) * rstd * g1v[lane]      + b1v[lane];
        float m1 = (x1 - mean) * rstd * g1v[lane + 64] + b1v[lane + 64];
        sM[r * 132 + lane]      = m0;
        sM[r * 132 + 64 + lane] = m1;
        sA[r * YS + lane]      = f2bf(m0);
        sA[r * YS + 64 + lane] = f2bf(m1);
    }
    __syncthreads();

    // ---- FFN ----
    fx16 accO = zv;
    for (int c = 0; c < 4; c++) {
        int hcol = 128 * c + 32 * wid + lane31;
        fx16 t = zv;
        {
            const unsigned short* a  = sA + lane31 * YS + lk;
            const unsigned short* bw = Winbf + (size_t)hcol * 128 + lk;
            #pragma unroll
            for (int ks = 0; ks < 8; ks++)
                t = mfma_bf16(*(const bh8*)(a + ks * 16), *(const bh8*)(bw + ks * 16), t);
        }
        float bias = Win_b[hcol];
        int colL = 32 * wid + lane31;
        #pragma unroll
        for (int r = 0; r < 16; r++) {
            int row = (r & 3) + 8 * (r >> 2) + 4 * (lane >> 5);
            sH[row * YS + colL] = f2bf(gelu_f(t[r] + bias));
        }
        __syncthreads();
        {
            const unsigned short* a  = sH + lane31 * YS + lk;
            const unsigned short* bw = Woutbf + (size_t)(32 * wid + lane31) * 512 + 128 * c + lk;
            #pragma unroll
            for (int ks = 0; ks < 8; ks++)
                accO = mfma_bf16(*(const bh8*)(a + ks * 16), *(const bh8*)(bw + ks * 16), accO);
        }
        __syncthreads();
    }
    {
        int col = 32 * wid + lane31;
        float bias = Wout_b[col];
        #pragma unroll
        for (int r = 0; r < 16; r++) {
            int row = (r & 3) + 8 * (r >> 2) + 4 * (lane >> 5);
            sO[row * 132 + col] = accO[r] + bias;
        }
    }
    __syncthreads();

    // ---- LN2 + mask_V -> hV_out, sV ----
    for (int r = wid; r < 32; r += 4) {
        float x0 = sO[r * 132 + lane]      + sM[r * 132 + lane];
        float x1 = sO[r * 132 + 64 + lane] + sM[r * 132 + 64 + lane];
        float s = x0 + x1, q = x0 * x0 + x1 * x1;
        #pragma unroll
        for (int off = 32; off; off >>= 1) { s += __shfl_down(s, off); q += __shfl_down(q, off); }
        s = __shfl(s, 0); q = __shfl(q, 0);
        float mean = s * 0.0078125f;
        float rstd = rsqrtf(q * 0.0078125f - mean * mean + 1e-5f);
        float mv = mask_V[p0 + r];
        float y0 = ((x0 - mean) * rstd * g2v[lane]      + b2v[lane])      * mv;
        float y1 = ((x1 - mean) * rstd * g2v[lane + 64] + b2v[lane + 64]) * mv;
        hV_out[(size_t)(p0 + r) * Hn + lane]      = y0;
        hV_out[(size_t)(p0 + r) * Hn + 64 + lane] = y1;
        sV[r * YS + lane]      = f2bf(y0);
        sV[r * YS + 64 + lane] = f2bf(y1);
    }
    __syncthreads();

    // ---- s11s/s11n = hV_out @ W11{self,nbr}^T ----
    {
        int col = 32 * wid + lane31;
        fx16 accS = zv, accN = zv;
        const unsigned short* a   = sV + lane31 * YS + lk;
        const unsigned short* bwS = W11bf + (size_t)col * 384 + lk;        // self cols 0..127
        const unsigned short* bwN = W11bf + (size_t)col * 384 + 256 + lk;  // nbr  cols 256..383
        #pragma unroll
        for (int ks = 0; ks < 8; ks++) {
            bh8 av = *(const bh8*)(a + ks * 16);
            accS = mfma_bf16(av, *(const bh8*)(bwS + ks * 16), accS);
            accN = mfma_bf16(av, *(const bh8*)(bwN + ks * 16), accN);
        }
        #pragma unroll
        for (int r = 0; r < 16; r++) {
            int row = (r & 3) + 8 * (r >> 2) + 4 * (lane >> 5);
            s11s[(size_t)(p0 + row) * Hn + col] = accS[r];
            s11n[(size_t)(p0 + row) * Hn + col] = accN[r];
        }
    }
}

// ---------------------------------------------------------------------------
// Kernel C: edge update (8 waves, 512 thr) — R4 structure, neighbor term
// gathered directly in GEMM1 epilogue (no prefetch regs).
// ---------------------------------------------------------------------------
__global__ __launch_bounds__(512, 8) void edge_update_mfma(
    const float* __restrict__ h_E, const int* __restrict__ E_idx,
    const unsigned short* __restrict__ wsbf,
    const float* __restrict__ s11s, const float* __restrict__ s11n,
    const float* __restrict__ W11_b, const float* __restrict__ W12_b,
    const float* __restrict__ W13_b,
    const float* __restrict__ g3v, const float* __restrict__ b3v,
    float* __restrict__ hE_out) {
    __shared__ __align__(16) unsigned short sX[64 * YS]; // h_E, live to end (residual)
    __shared__ __align__(16) unsigned short sY[64 * YS];
    __shared__ float sS11[256];
    __shared__ int   sIdx[64];

    const int tid = threadIdx.x;
    const int p0 = blockIdx.x * 2;
    const int bB = p0 >> 11;
    const unsigned short* W11bf = wsbf + OFF_W11;
    const unsigned short* W12bf = wsbf + OFF_W12;
    const unsigned short* W13bf = wsbf + OFF_W13;

    for (int i = tid; i < 1920; i += 512) {
        int r = i >> 5, c4 = (i & 31) << 2;
        float4 v = *(const float4*)(h_E + ((size_t)(p0 * Kn + r)) * Hn + c4);
        st_bf4(sX + r * YS + c4, v);
    }
    if (tid < 272)
        ((unsigned int*)(sX + 60 * YS))[tid] = 0;
    if (tid < 64) {
        int g = tid >> 5, c4 = (tid & 31) << 2;
        *(float4*)(sS11 + g * 128 + c4) = *(const float4*)(s11s + (size_t)(p0 + g) * Hn + c4);
    }
    if (tid < 64) sIdx[tid] = (tid < 60) ? E_idx[p0 * Kn + tid] : 0;
    __syncthreads();

    const int wid = tid >> 6, lane = tid & 63;
    const int mt = wid & 1, ct = wid >> 1;
    const int lane31 = lane & 31, lk = (lane >> 5) << 3;
    const int rowBase = 32 * mt;
    const fx16 zv = {};
    const int col = 32 * ct + lane31;

    fx16 acc = zv;
    gemm_one<8>(sX + (rowBase + lane31) * YS + lk,
                W11bf + (size_t)col * 384 + 128 + lk, acc);
    epi_gelu_sg(acc, col, rowBase, W11_b[col], sS11,
                s11n + (size_t)bB * NB * Hn + col, sIdx, sY, lane);
    __syncthreads();

    acc = zv;
    gemm_one<8>(sY + (rowBase + lane31) * YS + lk,
                W12bf + (size_t)col * 128 + lk, acc);
    __syncthreads();
    epi_gelu(acc, col, rowBase, W12_b[col], sY, lane);
    __syncthreads();

    acc = zv;
    gemm_one<8>(sY + (rowBase + lane31) * YS + lk,
                W13bf + (size_t)col * 128 + lk, acc);
    __syncthreads();
    epi_plain(acc, col, rowBase, W13_b[col], sY, lane);
    __syncthreads();

    // per-edge-row LN over E=128 (residual from bf16 h_E in sX)
    for (int r = wid; r < 60; r += 8) {
        float x0 = bf2f(sX[r * YS + lane])      + bf2f(sY[r * YS + lane]);
        float x1 = bf2f(sX[r * YS + 64 + lane]) + bf2f(sY[r * YS + 64 + lane]);
        float s = x0 + x1, q = x0 * x0 + x1 * x1;
        #pragma unroll
        for (int off = 32; off; off >>= 1) { s += __shfl_down(s, off); q += __shfl_down(q, off); }
        s = __shfl(s, 0); q = __shfl(q, 0);
        float mean = s * 0.0078125f;
        float rstd = rsqrtf(q * 0.0078125f - mean * mean + 1e-5f);
        float* op = hE_out + ((size_t)(p0 * Kn + r)) * 128;
        op[lane]      = (x0 - mean) * rstd * g3v[lane]      + b3v[lane];
        op[lane + 64] = (x1 - mean) * rstd * g3v[lane + 64] + b3v[lane + 64];
    }
}

extern "C" void kernel_launch(void* const* d_in, const int* in_sizes, int n_in,
                              void* d_out, int out_size, void* d_ws, size_t ws_size,
                              hipStream_t stream) {
    const float* h_V         = (const float*)d_in[0];
    const float* h_E         = (const float*)d_in[1];
    const int*   E_idx       = (const int*)  d_in[2];
    const float* mask_V      = (const float*)d_in[3];
    const float* mask_attend = (const float*)d_in[4];
    const float* W1_w  = (const float*)d_in[5];
    const float* W1_b  = (const float*)d_in[6];
    const float* W2_w  = (const float*)d_in[7];
    const float* W2_b  = (const float*)d_in[8];
    const float* W3_w  = (const float*)d_in[9];
    const float* W3_b  = (const float*)d_in[10];
    const float* W11_w = (const float*)d_in[11];
    const float* W11_b = (const float*)d_in[12];
    const float* W12_w = (const float*)d_in[13];
    const float* W12_b = (const float*)d_in[14];
    const float* W13_w = (const float*)d_in[15];
    const float* W13_b = (const float*)d_in[16];
    const float* Win_w  = (const float*)d_in[17];
    const float* Win_b  = (const float*)d_in[18];
    const float* Wout_w = (const float*)d_in[19];
    const float* Wout_b = (const float*)d_in[20];
    const float* g1 = (const float*)d_in[21];
    const float* b1 = (const float*)d_in[22];
    const float* g2 = (const float*)d_in[23];
    const float* b2 = (const float*)d_in[24];
    const float* g3 = (const float*)d_in[25];
    const float* b3 = (const float*)d_in[26];

    float* out    = (float*)d_out;
    float* hV_out = out;                          // [B,N,H]
    float* hE_out = out + (size_t)4 * 2048 * 128; // [B,N,K,E]
    unsigned short* wsbf = (unsigned short*)d_ws;
    float* wsf = (float*)(wsbf + W_TOTAL);
    unsigned short* zbf = (unsigned short*)wsf;   // [8192,128] bf16
    float* zm = wsf + WS_ZM;                      // [8192] fp32
    float* sS = wsf + WS_SS;   // s1 self, then (after B) s11 self
    float* sN = wsf + WS_SN;   // s1 nbr,  then (after B) s11 nbr

    prep_weights<<<(W_TOTAL + 255) / 256, 256, 0, stream>>>(
        W1_w, W2_w, W3_w, W11_w, W12_w, W13_w, Win_w, Wout_w, wsbf);

    self_gemm<<<256, 256, 0, stream>>>(h_V, wsbf, sS, sN);

    node_msg_mfma<<<4096, 512, 0, stream>>>(
        h_E, E_idx, mask_attend, wsbf, sS, sN, W1_b, W2_b, zbf, zm);

    node_fin_ffn<<<256, 256, 0, stream>>>(
        zbf, zm, h_V, mask_V, wsbf, W3_b, Win_b, Wout_b,
        g1, b1, g2, b2, hV_out, sS, sN);

    edge_update_mfma<<<4096, 512, 0, stream>>>(
        h_E, E_idx, wsbf, sS, sN,
        W11_b, W12_b, W13_b, g3, b3, hE_out);
}